// Round 3
// baseline (1044.800 us; speedup 1.0000x reference)
//
#include <hip/hip_runtime.h>
#include <hip/hip_bf16.h>
#include <math.h>

// Problem constants
#define BATCH 8
#define CDIM 256
#define HEADS 8
#define CH 32              // CDIM/HEADS
#define NSP 4096           // 64*64
#define HID 680
#define QKV_CH 768         // 3*CDIM
#define FFN_CH 1360        // 2*HID
#define HIDP 704           // HID padded to mult of 32 (K-pad for GEMM3)
#define FFNP 1408          // FFN_CH padded to mult of 128 (N-pad for GEMM2 weights)

typedef _Float16 half8 __attribute__((ext_vector_type(8)));
typedef float floatx4 __attribute__((ext_vector_type(4)));

// async global->LDS, 16B per lane; lds dest = wave-uniform base + lane*16
__device__ inline void gload_lds16(const _Float16* g, _Float16* l) {
  __builtin_amdgcn_global_load_lds(
      (const __attribute__((address_space(1))) unsigned int*)g,
      (__attribute__((address_space(3))) unsigned int*)l, 16, 0, 0);
}

// ---------------------------------------------------------------------------
// LayerNorm over channel dim, per spatial location. X: [B,256,4096] f32
// ---------------------------------------------------------------------------
__global__ __launch_bounds__(256) void ln_kernel(
    const float* __restrict__ X, const float* __restrict__ w,
    const float* __restrict__ bia, float* __restrict__ Y) {
  int idx = blockIdx.x * 256 + threadIdx.x;   // [0, B*4096)
  int b = idx >> 12;
  int p = idx & 4095;
  const float* xp = X + ((size_t)b * CDIM) * NSP + p;
  float s = 0.f, s2 = 0.f;
  for (int c = 0; c < CDIM; ++c) {
    float v = xp[(size_t)c * NSP];
    s += v; s2 += v * v;
  }
  float mu  = s * (1.f / CDIM);
  float var = s2 * (1.f / CDIM) - mu * mu;
  float inv = 1.0f / sqrtf(var + 1e-5f);
  float* yp = Y + ((size_t)b * CDIM) * NSP + p;
  for (int c = 0; c < CDIM; ++c) {
    float v = xp[(size_t)c * NSP];
    yp[(size_t)c * NSP] = (v - mu) * inv * w[c] + bia[c];
  }
}

// ---------------------------------------------------------------------------
// Depthwise 3x3 (SAME) on concat(xn, yn, yn) -> qkv [B,768,4096] f32
// ---------------------------------------------------------------------------
__global__ __launch_bounds__(256) void dwconv_qkv_kernel(
    const float* __restrict__ xn, const float* __restrict__ yn,
    const float* __restrict__ kw, float* __restrict__ out) {
  int idx = blockIdx.x * 256 + threadIdx.x;   // [0, B*768*4096)
  int x0 = idx & 63;
  int y0 = (idx >> 6) & 63;
  int cp = idx >> 12;          // b*768 + c
  int b  = cp / QKV_CH;
  int c  = cp - b * QKV_CH;
  int ch = c & 255;
  const float* src = ((c < 256) ? xn : yn) + ((size_t)(b * CDIM + ch)) * NSP;
  const float* k9  = kw + c * 9;
  float acc = 0.f;
#pragma unroll
  for (int ky = -1; ky <= 1; ++ky) {
    int yy = y0 + ky;
    if ((unsigned)yy > 63u) continue;
#pragma unroll
    for (int kx = -1; kx <= 1; ++kx) {
      int xx = x0 + kx;
      if ((unsigned)xx > 63u) continue;
      acc += src[yy * 64 + xx] * k9[(ky + 1) * 3 + (kx + 1)];
    }
  }
  out[idx] = acc;
}

// ---------------------------------------------------------------------------
// L2 norms of q (ch 0..255) and k (ch 256..511) rows over n=4096
// ---------------------------------------------------------------------------
__global__ __launch_bounds__(256) void norm_kernel(
    const float* __restrict__ qkv, float* __restrict__ nrm) {
  __shared__ float sb[4];
  int bi = blockIdx.x;            // [0, 4096)
  int which = bi >> 11;           // 0=q, 1=k
  int bc = bi & 2047;             // b*256 + c
  int b = bc >> 8;
  int c = bc & 255;
  const float* p = qkv + ((size_t)(b * QKV_CH + which * 256 + c)) * NSP;
  float s = 0.f;
  for (int j = threadIdx.x; j < NSP; j += 256) { float v = p[j]; s += v * v; }
  for (int off = 32; off > 0; off >>= 1) s += __shfl_down(s, off, 64);
  int lane = threadIdx.x & 63, wid = threadIdx.x >> 6;
  if (lane == 0) sb[wid] = s;
  __syncthreads();
  if (threadIdx.x == 0) {
    float t = sb[0] + sb[1] + sb[2] + sb[3];
    nrm[which * 2048 + bc] = fmaxf(sqrtf(t), 1e-12f);
  }
}

// ---------------------------------------------------------------------------
// attn[b,h,c,:] = softmax_d( dot(q_c,k_d)/(|q_c||k_d|) * temp[h] )
// ---------------------------------------------------------------------------
__global__ __launch_bounds__(256) void attn_kernel(
    const float* __restrict__ qkv, const float* __restrict__ nrm,
    const float* __restrict__ temp, float* __restrict__ attn) {
  __shared__ float qs[NSP];
  __shared__ float dots[32];
  int bi = blockIdx.x;            // ((b*8+h)*32+c)
  int c = bi & 31;
  int h = (bi >> 5) & 7;
  int b = bi >> 8;
  int gq = h * CH + c;
  const float* qp = qkv + ((size_t)(b * QKV_CH + gq)) * NSP;
  for (int j = threadIdx.x; j < NSP; j += 256) qs[j] = qp[j];
  __syncthreads();
  int wid = threadIdx.x >> 6, lane = threadIdx.x & 63;
  const float* kbase = qkv + ((size_t)(b * QKV_CH + 256 + h * CH)) * NSP;
  for (int d = wid; d < 32; d += 4) {
    const float* kp = kbase + (size_t)d * NSP;
    float s = 0.f;
    for (int j = lane; j < NSP; j += 64) s += qs[j] * kp[j];
    for (int off = 32; off > 0; off >>= 1) s += __shfl_down(s, off, 64);
    if (lane == 0) dots[d] = s;
  }
  __syncthreads();
  if (threadIdx.x < 32) {
    int d = threadIdx.x;
    float qn = nrm[b * 256 + gq];
    float kn = nrm[2048 + b * 256 + h * CH + d];
    float v = dots[d] / (qn * kn) * temp[h];
    float m = v;
    for (int mk = 16; mk > 0; mk >>= 1) m = fmaxf(m, __shfl_xor(m, mk, 64));
    float e = expf(v - m);
    float ss = e;
    for (int mk = 16; mk > 0; mk >>= 1) ss += __shfl_xor(ss, mk, 64);
    attn[(size_t)bi * 32 + d] = e / ss;
  }
}

// ---------------------------------------------------------------------------
// avout_h[b][n][c] (f16, [n][c] layout!) = sum_d attn[b,h,c,d] * v[b,h,d,n]
// LDS transpose so global writes are 16B-granular.
// ---------------------------------------------------------------------------
__global__ __launch_bounds__(256) void av_kernel(
    const float* __restrict__ qkv, const float* __restrict__ attn,
    _Float16* __restrict__ outh) {
  __shared__ float a_s[1024];
  __shared__ float tr[256 * 33];   // +1 pad word per row -> conflict-free
  int bi = blockIdx.x;           // (b*8+h)*16 + chunk
  int chunk = bi & 15;
  int h = (bi >> 4) & 7;
  int b = bi >> 7;
  int tid = threadIdx.x;
  for (int j = tid; j < 1024; j += 256)
    a_s[j] = attn[((size_t)(b * 8 + h)) * 1024 + j];
  __syncthreads();
  int n = chunk * 256 + tid;
  const float* vbase = qkv + ((size_t)(b * QKV_CH + 512 + h * CH)) * NSP + n;
  float acc[32];
#pragma unroll
  for (int c = 0; c < 32; ++c) acc[c] = 0.f;
#pragma unroll 4
  for (int d = 0; d < 32; ++d) {
    float vv = vbase[(size_t)d * NSP];
#pragma unroll
    for (int c = 0; c < 32; ++c) acc[c] += a_s[c * 32 + d] * vv;
  }
#pragma unroll
  for (int c = 0; c < 32; ++c) tr[tid * 33 + c] = acc[c];
  __syncthreads();
#pragma unroll
  for (int it = 0; it < 4; ++it) {
    int gi = it * 256 + tid;
    int row = gi >> 2, gc = gi & 3;
    half8 hv;
#pragma unroll
    for (int e = 0; e < 8; ++e) hv[e] = (_Float16)tr[row * 33 + gc * 8 + e];
    *(half8*)(outh + ((size_t)(b * NSP + chunk * 256 + row)) * CDIM + h * CH + gc * 8) = hv;
  }
}

// ---------------------------------------------------------------------------
// Weight f32 -> f16 with zero padding. dst [Rd][Cd], src [R][Cs]
// ---------------------------------------------------------------------------
__global__ __launch_bounds__(256) void convw_kernel(
    const float* __restrict__ src, _Float16* __restrict__ dst,
    int R, int Cs, int Cd, int total) {
  int idx = blockIdx.x * 256 + threadIdx.x;
  if (idx >= total) return;
  int r = idx / Cd, c = idx - r * Cd;
  float v = (r < R && c < Cs) ? src[r * Cs + c] : 0.f;
  dst[idx] = (_Float16)v;
}

// ---------------------------------------------------------------------------
// x2 = x + P; P is overwritten IN-PLACE with x2 (f32 [c][n]).
// LN over c -> x2nh [b][n][c] f16 (GEMM2 A-operand) via per-wave LDS transpose
// ---------------------------------------------------------------------------
__global__ __launch_bounds__(256) void ln2_kernel(
    const float* __restrict__ X, float* __restrict__ P,
    const float* __restrict__ w2, const float* __restrict__ b2,
    _Float16* __restrict__ x2nh) {
  __shared__ __align__(16) _Float16 lw[4][64 * 72];  // 72 = 64 + pad (16B-mult rows)
  int tid = threadIdx.x;
  int lane = tid & 63, w = tid >> 6;
  int loc = blockIdx.x * 256 + w * 64 + lane;   // [0, 32768) = b*4096+p
  int b = loc >> 12, p = loc & 4095;
  const float* xp = X + ((size_t)b * CDIM) * NSP + p;
  float* pp = P + ((size_t)b * CDIM) * NSP + p;
  float s = 0.f, s2 = 0.f;
  for (int c = 0; c < CDIM; ++c) {
    float v = xp[(size_t)c * NSP] + pp[(size_t)c * NSP];
    s += v; s2 += v * v;
  }
  float mu = s * (1.f / CDIM);
  float var = s2 * (1.f / CDIM) - mu * mu;
  float inv = 1.0f / sqrtf(var + 1e-5f);
  _Float16* lwp = lw[w];
  int locb = blockIdx.x * 256 + w * 64;         // wave's global location base
  for (int cc0 = 0; cc0 < CDIM; cc0 += 64) {
    for (int c = cc0; c < cc0 + 64; ++c) {
      float v = xp[(size_t)c * NSP] + pp[(size_t)c * NSP];
      pp[(size_t)c * NSP] = v;    // x2 in-place (each element touched once)
      lwp[lane * 72 + (c - cc0)] = (_Float16)((v - mu) * inv * w2[c] + b2[c]);
    }
    // wave-synchronous flush (same wave wrote lw; lgkmcnt ordering suffices)
#pragma unroll
    for (int it = 0; it < 8; ++it) {
      int m = it * 64 + lane;
      int row = m >> 3, cg = m & 7;
      half8 hv = *(const half8*)(lwp + row * 72 + cg * 8);
      *(half8*)(x2nh + ((size_t)(locb + row)) * CDIM + cc0 + cg * 8) = hv;
    }
  }
}

// ---------------------------------------------------------------------------
// Unified f16 MFMA GEMM: D[i][j] = sum_k A[i][k]*B[j][k] (+R), OutT out.
// 128x128 tile, BK=32, 4 waves (2x2 of 64x64), global_load_lds staging.
// ---------------------------------------------------------------------------
template <bool RES, typename OutT>
__global__ __launch_bounds__(256) void gemm_f16_kernel(
    const _Float16* __restrict__ A, size_t sA,
    const _Float16* __restrict__ B, size_t sB,
    const float* __restrict__ R, size_t sR,
    OutT* __restrict__ Y, size_t sY,
    int K, int ldy, int Nj) {
  __shared__ __align__(16) _Float16 As[128 * 32];
  __shared__ __align__(16) _Float16 Bs[128 * 32];
  int tid = threadIdx.x;
  int lane = tid & 63;
  int w = tid >> 6;
  int wr = w >> 1, wc = w & 1;
  int lm = lane & 15, g = lane >> 4;
  int i0 = blockIdx.y * 128;
  int j0 = blockIdx.x * 128;
  int b  = blockIdx.z;
  const _Float16* Ab = A + (size_t)b * sA;
  const _Float16* Bb = B + (size_t)b * sB;

  floatx4 acc[4][4];
#pragma unroll
  for (int mi = 0; mi < 4; ++mi)
#pragma unroll
    for (int ni = 0; ni < 4; ++ni) acc[mi][ni] = {0.f, 0.f, 0.f, 0.f};

  for (int k0 = 0; k0 < K; k0 += 32) {
    // stage 128x32 f16 A and B tiles: 512 16B-granules each, 2 per thread
#pragma unroll
    for (int jj = 0; jj < 2; ++jj) {
      int idx = jj * 256 + tid;
      int row = idx >> 2, gc = idx & 3;
      int base = idx & ~63;        // wave-chunk granule base (uniform per wave)
      gload_lds16(Ab + (size_t)(i0 + row) * K + k0 + gc * 8, As + base * 8);
      gload_lds16(Bb + (size_t)(j0 + row) * K + k0 + gc * 8, Bs + base * 8);
    }
    __syncthreads();               // compiler emits vmcnt(0) drain before barrier
    half8 ha[4], hb[4];
#pragma unroll
    for (int mi = 0; mi < 4; ++mi)
      ha[mi] = *(const half8*)(As + (wr * 64 + mi * 16 + lm) * 32 + g * 8);
#pragma unroll
    for (int ni = 0; ni < 4; ++ni)
      hb[ni] = *(const half8*)(Bs + (wc * 64 + ni * 16 + lm) * 32 + g * 8);
#pragma unroll
    for (int mi = 0; mi < 4; ++mi)
#pragma unroll
      for (int ni = 0; ni < 4; ++ni)
        acc[mi][ni] = __builtin_amdgcn_mfma_f32_16x16x32_f16(
            ha[mi], hb[ni], acc[mi][ni], 0, 0, 0);
    __syncthreads();
  }

  const float* Rb = RES ? (R + (size_t)b * sR) : nullptr;
  OutT* Yb = Y + (size_t)b * sY;
#pragma unroll
  for (int mi = 0; mi < 4; ++mi) {
#pragma unroll
    for (int ni = 0; ni < 4; ++ni) {
      int j = j0 + wc * 64 + ni * 16 + lm;
      if (j >= Nj) continue;
#pragma unroll
      for (int r = 0; r < 4; ++r) {
        int i = i0 + wr * 64 + mi * 16 + g * 4 + r;   // D row = (lane>>4)*4+r
        size_t o = (size_t)i * ldy + j;
        float v = acc[mi][ni][r];
        if (RES) v += Rb[o];
        Yb[o] = (OutT)v;
      }
    }
  }
}

// ---------------------------------------------------------------------------
// Depthwise 3x3 + exact-gelu gate, [n][c] layout, f16 t.
// t [b*4096][1360] f16 -> g [b*4096][704] f16 (cols 680..703 zeroed = K-pad)
// ---------------------------------------------------------------------------
__global__ __launch_bounds__(256) void dwgate_kernel(
    const _Float16* __restrict__ t, const float* __restrict__ kw,
    _Float16* __restrict__ g) {
  int c = blockIdx.x * 256 + threadIdx.x;   // [0,768)
  if (c >= HIDP) return;
  int bp = blockIdx.y;                       // b*4096 + p
  _Float16* gp = g + (size_t)bp * HIDP;
  if (c >= HID) { gp[c] = (_Float16)0.f; return; }
  int p = bp & 4095;
  int yy0 = p >> 6, xx0 = p & 63;
  const _Float16* tb = t + (size_t)bp * FFN_CH;
  const float* k1 = kw + c * 9;
  const float* k2 = kw + (HID + c) * 9;
  float a = 0.f, bb = 0.f;
#pragma unroll
  for (int dy = -1; dy <= 1; ++dy) {
    int yy = yy0 + dy;
    if ((unsigned)yy > 63u) continue;
#pragma unroll
    for (int dx = -1; dx <= 1; ++dx) {
      int xx = xx0 + dx;
      if ((unsigned)xx > 63u) continue;
      const _Float16* trp = tb + (ptrdiff_t)(dy * 64 + dx) * FFN_CH;
      int ki = (dy + 1) * 3 + (dx + 1);
      a  += (float)trp[c] * k1[ki];
      bb += (float)trp[HID + c] * k2[ki];
    }
  }
  float ge = 0.5f * a * (1.f + erff(a * 0.70710678118654752440f));
  gp[c] = (_Float16)(ge * bb);
}

// ---------------------------------------------------------------------------
extern "C" void kernel_launch(void* const* d_in, const int* in_sizes, int n_in,
                              void* d_out, int out_size, void* d_ws, size_t ws_size,
                              hipStream_t stream) {
  const float* x         = (const float*)d_in[0];
  const float* y         = (const float*)d_in[1];
  const float* ln1x_w    = (const float*)d_in[2];
  const float* ln1x_b    = (const float*)d_in[3];
  const float* ln1y_w    = (const float*)d_in[4];
  const float* ln1y_b    = (const float*)d_in[5];
  const float* ln2_w     = (const float*)d_in[6];
  const float* ln2_b     = (const float*)d_in[7];
  const float* temperature = (const float*)d_in[8];
  const float* qkv_dw    = (const float*)d_in[9];
  const float* attn_proj_w = (const float*)d_in[10];
  const float* ffn_in_w  = (const float*)d_in[11];
  const float* ffn_dw    = (const float*)d_in[12];
  const float* ffn_out_w = (const float*)d_in[13];
  float* out = (float*)d_out;
  char* wsb = (char*)d_ws;

  // ---- compact workspace layout (bytes); total ~205 MiB ----
  // Region A [0, 32M):        xn (f32) -> P -> x2 (in-place)
  // Region B [32M, 64M):      yn (f32) -> x2n_h (f16, 16M)
  // Region C [64M, 160M):     qkv (f32, 96M) -> tbuf (f16, 87M)
  // Region D [160M, 204M):    av_h (f16, 16M) -> g_h (f16, 44M)
  // smalls   [204M, 206M):    nrm, attn, wp_h, wf_h, wo_h
  const size_t SZ_CN4 = (size_t)BATCH * CDIM * NSP * 4;          // 33,554,432
  const size_t off_A   = 0;
  const size_t off_B   = SZ_CN4;
  const size_t off_C   = 2 * SZ_CN4;
  const size_t off_D   = off_C + (size_t)BATCH * QKV_CH * NSP * 4;
  const size_t off_sm  = off_D + (size_t)BATCH * NSP * HIDP * 2; // g_h is max user of D
  const size_t off_nrm  = off_sm;
  const size_t off_attn = off_nrm + 16384;
  const size_t off_wp   = off_attn + 262144;
  const size_t off_wf   = off_wp + (size_t)CDIM * CDIM * 2;
  const size_t off_wo   = off_wf + (size_t)FFNP * CDIM * 2;

  float*    xn    = (float*)(wsb + off_A);
  float*    yn    = (float*)(wsb + off_B);
  float*    qkv   = (float*)(wsb + off_C);
  _Float16* tbuf  = (_Float16*)(wsb + off_C);   // after qkv dead
  _Float16* av_h  = (_Float16*)(wsb + off_D);
  _Float16* g_h   = (_Float16*)(wsb + off_D);   // after av_h dead
  float*    P     = (float*)(wsb + off_A);      // after xn dead; becomes x2
  _Float16* x2n_h = (_Float16*)(wsb + off_B);   // after yn dead
  float*    nrm   = (float*)(wsb + off_nrm);
  float*    attn  = (float*)(wsb + off_attn);
  _Float16* wp_h  = (_Float16*)(wsb + off_wp);
  _Float16* wf_h  = (_Float16*)(wsb + off_wf);
  _Float16* wo_h  = (_Float16*)(wsb + off_wo);

  // ---- weight conversions (f32 -> f16, zero-padded) ----
  convw_kernel<<<(CDIM * CDIM + 255) / 256, 256, 0, stream>>>(
      attn_proj_w, wp_h, CDIM, CDIM, CDIM, CDIM * CDIM);
  convw_kernel<<<(FFNP * CDIM + 255) / 256, 256, 0, stream>>>(
      ffn_in_w, wf_h, FFN_CH, CDIM, CDIM, FFNP * CDIM);
  convw_kernel<<<(CDIM * HIDP + 255) / 256, 256, 0, stream>>>(
      ffn_out_w, wo_h, CDIM, HID, HIDP, CDIM * HIDP);

  // ---- attention branch ----
  ln_kernel<<<BATCH * NSP / 256, 256, 0, stream>>>(x, ln1x_w, ln1x_b, xn);
  ln_kernel<<<BATCH * NSP / 256, 256, 0, stream>>>(y, ln1y_w, ln1y_b, yn);
  dwconv_qkv_kernel<<<BATCH * QKV_CH * NSP / 256, 256, 0, stream>>>(xn, yn, qkv_dw, qkv);
  norm_kernel<<<4096, 256, 0, stream>>>(qkv, nrm);
  attn_kernel<<<BATCH * HEADS * CH, 256, 0, stream>>>(qkv, nrm, temperature, attn);
  av_kernel<<<BATCH * HEADS * (NSP / 256), 256, 0, stream>>>(qkv, attn, av_h);

  // GEMM1 (flipped): P[b][o][n] = sum_k Wproj[o][k] * av_h[b][n][k]
  {
    dim3 grid(NSP / 128, CDIM / 128, BATCH);
    gemm_f16_kernel<false, float><<<grid, 256, 0, stream>>>(
        wp_h, (size_t)0, av_h, (size_t)NSP * CDIM, nullptr, (size_t)0,
        P, (size_t)CDIM * NSP, CDIM, NSP, NSP);
  }

  // LN2 fused residual: x2 = x + P (in-place into P); x2n_h (f16 [n][c])
  ln2_kernel<<<BATCH * NSP / 256, 256, 0, stream>>>(x, P, ln2_w, ln2_b, x2n_h);

  // GEMM2: t[b][n][o] = sum_k x2n_h[b][n][k] * wf_h[o][k]  (f16 out, o<1360)
  {
    dim3 grid(FFNP / 128, NSP / 128, BATCH);
    gemm_f16_kernel<false, _Float16><<<grid, 256, 0, stream>>>(
        x2n_h, (size_t)NSP * CDIM, wf_h, (size_t)0, nullptr, (size_t)0,
        tbuf, (size_t)NSP * FFN_CH, CDIM, FFN_CH, FFN_CH);
  }

  // depthwise 3x3 + gelu gate -> g_h [b][n][704] f16 (zero-padded cols)
  {
    dim3 grid(3, BATCH * NSP);
    dwgate_kernel<<<grid, 256, 0, stream>>>(tbuf, ffn_dw, g_h);
  }

  // GEMM3 (flipped, +residual): out[b][o][n] = x2 + sum_k wo_h[o][k]*g_h[b][n][k]
  {
    dim3 grid(NSP / 128, CDIM / 128, BATCH);
    gemm_f16_kernel<true, float><<<grid, 256, 0, stream>>>(
        wo_h, (size_t)0, g_h, (size_t)NSP * HIDP, P, (size_t)CDIM * NSP,
        out, (size_t)CDIM * NSP, HIDP, NSP, NSP);
  }
}

// Round 4
// 627.893 us; speedup vs baseline: 1.6640x; 1.6640x over previous
//
#include <hip/hip_runtime.h>
#include <hip/hip_bf16.h>
#include <math.h>

// Problem constants
#define BATCH 8
#define CDIM 256
#define HEADS 8
#define CH 32              // CDIM/HEADS
#define NSP 4096           // 64*64
#define HID 680
#define QKV_CH 768         // 3*CDIM
#define FFN_CH 1360        // 2*HID
#define HIDP 704           // HID padded to mult of 32 (K-pad for GEMM3)
#define FFNP 1408          // FFN_CH padded to mult of 128 (N-pad for GEMM2 weights)

typedef _Float16 half8 __attribute__((ext_vector_type(8)));
typedef float floatx4 __attribute__((ext_vector_type(4)));

// async global->LDS, 16B per lane; lds dest = wave-uniform base + lane*16
__device__ inline void gload_lds16(const _Float16* g, _Float16* l) {
  __builtin_amdgcn_global_load_lds(
      (const __attribute__((address_space(1))) unsigned int*)g,
      (__attribute__((address_space(3))) unsigned int*)l, 16, 0, 0);
}

// ---------------------------------------------------------------------------
// LayerNorm over channel dim, per spatial location. X: [B,256,4096] f32
// ---------------------------------------------------------------------------
__global__ __launch_bounds__(256) void ln_kernel(
    const float* __restrict__ X, const float* __restrict__ w,
    const float* __restrict__ bia, float* __restrict__ Y) {
  int idx = blockIdx.x * 256 + threadIdx.x;   // [0, B*4096)
  int b = idx >> 12;
  int p = idx & 4095;
  const float* xp = X + ((size_t)b * CDIM) * NSP + p;
  float s = 0.f, s2 = 0.f;
  for (int c = 0; c < CDIM; ++c) {
    float v = xp[(size_t)c * NSP];
    s += v; s2 += v * v;
  }
  float mu  = s * (1.f / CDIM);
  float var = s2 * (1.f / CDIM) - mu * mu;
  float inv = 1.0f / sqrtf(var + 1e-5f);
  float* yp = Y + ((size_t)b * CDIM) * NSP + p;
  for (int c = 0; c < CDIM; ++c) {
    float v = xp[(size_t)c * NSP];
    yp[(size_t)c * NSP] = (v - mu) * inv * w[c] + bia[c];
  }
}

// ---------------------------------------------------------------------------
// Depthwise 3x3 (SAME) on concat(xn, yn, yn) -> qkv [B,768,4096] f32
// One block per (b, out-channel): stage 64x64 image in zero-padded LDS,
// 16 outputs/thread from aligned float4 LDS reads. Image read once from HBM.
// ---------------------------------------------------------------------------
__global__ __launch_bounds__(256) void dwconv_qkv_kernel(
    const float* __restrict__ xn, const float* __restrict__ yn,
    const float* __restrict__ kw, float* __restrict__ out) {
  __shared__ float sm[66 * 68];       // 66 rows x 68 cols, zero border
  int bc = blockIdx.x;                // b*768 + c
  int b = bc / QKV_CH;
  int c = bc - b * QKV_CH;
  int ch = (c < 256) ? c : ((c < 512) ? c - 256 : c - 512);
  const float* src = ((c < 256) ? xn : yn) + ((size_t)(b * CDIM + ch)) * NSP;
  int tid = threadIdx.x;
  // zero fill (border matters; interior overwritten below)
  for (int i = tid; i < 66 * 68; i += 256) sm[i] = 0.f;
  __syncthreads();
  // load interior: thread -> row r=tid>>2, 16 cols at xq=(tid&3)*16
  {
    int r = tid >> 2, xq = (tid & 3) * 16;
    const float* sp = src + r * 64 + xq;
    float4 v0 = ((const float4*)sp)[0];
    float4 v1 = ((const float4*)sp)[1];
    float4 v2 = ((const float4*)sp)[2];
    float4 v3 = ((const float4*)sp)[3];
    float* lp = sm + (r + 1) * 68 + 1 + xq;
    lp[0]=v0.x; lp[1]=v0.y; lp[2]=v0.z;  lp[3]=v0.w;
    lp[4]=v1.x; lp[5]=v1.y; lp[6]=v1.z;  lp[7]=v1.w;
    lp[8]=v2.x; lp[9]=v2.y; lp[10]=v2.z; lp[11]=v2.w;
    lp[12]=v3.x;lp[13]=v3.y;lp[14]=v3.z; lp[15]=v3.w;
  }
  __syncthreads();
  float k9[9];
#pragma unroll
  for (int i = 0; i < 9; ++i) k9[i] = kw[c * 9 + i];   // uniform -> s_load
  int r = tid >> 2, xs = (tid & 3) * 16;
  // rows needed: input rows r-1..r+1 = lds rows r..r+2; cols xs-1..xs+16
  // = lds indices row*68 + xs + (0..17), 16B-aligned base.
  float row0[18], row1[18], row2[18];
  {
    const float* q0 = sm + (r + 0) * 68 + xs;
    const float* q1 = sm + (r + 1) * 68 + xs;
    const float* q2 = sm + (r + 2) * 68 + xs;
#pragma unroll
    for (int j = 0; j < 4; ++j) {
      float4 a0 = *(const float4*)(q0 + j * 4);
      float4 a1 = *(const float4*)(q1 + j * 4);
      float4 a2 = *(const float4*)(q2 + j * 4);
      row0[j*4+0]=a0.x; row0[j*4+1]=a0.y; row0[j*4+2]=a0.z; row0[j*4+3]=a0.w;
      row1[j*4+0]=a1.x; row1[j*4+1]=a1.y; row1[j*4+2]=a1.z; row1[j*4+3]=a1.w;
      row2[j*4+0]=a2.x; row2[j*4+1]=a2.y; row2[j*4+2]=a2.z; row2[j*4+3]=a2.w;
    }
    row0[16]=q0[16]; row0[17]=q0[17];
    row1[16]=q1[16]; row1[17]=q1[17];
    row2[16]=q2[16]; row2[17]=q2[17];
  }
  float acc[16];
#pragma unroll
  for (int i = 0; i < 16; ++i) {
    acc[i] = row0[i]*k9[0] + row0[i+1]*k9[1] + row0[i+2]*k9[2]
           + row1[i]*k9[3] + row1[i+1]*k9[4] + row1[i+2]*k9[5]
           + row2[i]*k9[6] + row2[i+1]*k9[7] + row2[i+2]*k9[8];
  }
  float* op = out + (size_t)bc * NSP + r * 64 + xs;
#pragma unroll
  for (int j = 0; j < 4; ++j)
    ((float4*)op)[j] = make_float4(acc[j*4+0], acc[j*4+1], acc[j*4+2], acc[j*4+3]);
}

// ---------------------------------------------------------------------------
// L2 norms of q (ch 0..255) and k (ch 256..511) rows over n=4096
// ---------------------------------------------------------------------------
__global__ __launch_bounds__(256) void norm_kernel(
    const float* __restrict__ qkv, float* __restrict__ nrm) {
  __shared__ float sb[4];
  int bi = blockIdx.x;            // [0, 4096)
  int which = bi >> 11;           // 0=q, 1=k
  int bc = bi & 2047;             // b*256 + c
  int b = bc >> 8;
  int c = bc & 255;
  const float* p = qkv + ((size_t)(b * QKV_CH + which * 256 + c)) * NSP;
  float s = 0.f;
  for (int j = threadIdx.x; j < NSP; j += 256) { float v = p[j]; s += v * v; }
  for (int off = 32; off > 0; off >>= 1) s += __shfl_down(s, off, 64);
  int lane = threadIdx.x & 63, wid = threadIdx.x >> 6;
  if (lane == 0) sb[wid] = s;
  __syncthreads();
  if (threadIdx.x == 0) {
    float t = sb[0] + sb[1] + sb[2] + sb[3];
    nrm[which * 2048 + bc] = fmaxf(sqrtf(t), 1e-12f);
  }
}

// ---------------------------------------------------------------------------
// attn[b,h,c,:] = softmax_d( dot(q_c,k_d)/(|q_c||k_d|) * temp[h] )
// ---------------------------------------------------------------------------
__global__ __launch_bounds__(256) void attn_kernel(
    const float* __restrict__ qkv, const float* __restrict__ nrm,
    const float* __restrict__ temp, float* __restrict__ attn) {
  __shared__ float qs[NSP];
  __shared__ float dots[32];
  int bi = blockIdx.x;            // ((b*8+h)*32+c)
  int c = bi & 31;
  int h = (bi >> 5) & 7;
  int b = bi >> 8;
  int gq = h * CH + c;
  const float* qp = qkv + ((size_t)(b * QKV_CH + gq)) * NSP;
  for (int j = threadIdx.x; j < NSP; j += 256) qs[j] = qp[j];
  __syncthreads();
  int wid = threadIdx.x >> 6, lane = threadIdx.x & 63;
  const float* kbase = qkv + ((size_t)(b * QKV_CH + 256 + h * CH)) * NSP;
  for (int d = wid; d < 32; d += 4) {
    const float* kp = kbase + (size_t)d * NSP;
    float s = 0.f;
    for (int j = lane; j < NSP; j += 64) s += qs[j] * kp[j];
    for (int off = 32; off > 0; off >>= 1) s += __shfl_down(s, off, 64);
    if (lane == 0) dots[d] = s;
  }
  __syncthreads();
  if (threadIdx.x < 32) {
    int d = threadIdx.x;
    float qn = nrm[b * 256 + gq];
    float kn = nrm[2048 + b * 256 + h * CH + d];
    float v = dots[d] / (qn * kn) * temp[h];
    float m = v;
    for (int mk = 16; mk > 0; mk >>= 1) m = fmaxf(m, __shfl_xor(m, mk, 64));
    float e = expf(v - m);
    float ss = e;
    for (int mk = 16; mk > 0; mk >>= 1) ss += __shfl_xor(ss, mk, 64);
    attn[(size_t)bi * 32 + d] = e / ss;
  }
}

// ---------------------------------------------------------------------------
// avout_h[b][n][c] (f16, [n][c] layout!) = sum_d attn[b,h,c,d] * v[b,h,d,n]
// LDS transpose so global writes are 16B-granular.
// ---------------------------------------------------------------------------
__global__ __launch_bounds__(256) void av_kernel(
    const float* __restrict__ qkv, const float* __restrict__ attn,
    _Float16* __restrict__ outh) {
  __shared__ float a_s[1024];
  __shared__ float tr[256 * 33];   // +1 pad word per row -> conflict-free
  int bi = blockIdx.x;           // (b*8+h)*16 + chunk
  int chunk = bi & 15;
  int h = (bi >> 4) & 7;
  int b = bi >> 7;
  int tid = threadIdx.x;
  for (int j = tid; j < 1024; j += 256)
    a_s[j] = attn[((size_t)(b * 8 + h)) * 1024 + j];
  __syncthreads();
  int n = chunk * 256 + tid;
  const float* vbase = qkv + ((size_t)(b * QKV_CH + 512 + h * CH)) * NSP + n;
  float acc[32];
#pragma unroll
  for (int c = 0; c < 32; ++c) acc[c] = 0.f;
#pragma unroll 4
  for (int d = 0; d < 32; ++d) {
    float vv = vbase[(size_t)d * NSP];
#pragma unroll
    for (int c = 0; c < 32; ++c) acc[c] += a_s[c * 32 + d] * vv;
  }
#pragma unroll
  for (int c = 0; c < 32; ++c) tr[tid * 33 + c] = acc[c];
  __syncthreads();
#pragma unroll
  for (int it = 0; it < 4; ++it) {
    int gi = it * 256 + tid;
    int row = gi >> 2, gc = gi & 3;
    half8 hv;
#pragma unroll
    for (int e = 0; e < 8; ++e) hv[e] = (_Float16)tr[row * 33 + gc * 8 + e];
    *(half8*)(outh + ((size_t)(b * NSP + chunk * 256 + row)) * CDIM + h * CH + gc * 8) = hv;
  }
}

// ---------------------------------------------------------------------------
// Weight f32 -> f16 with zero padding. dst [Rd][Cd], src [R][Cs]
// ---------------------------------------------------------------------------
__global__ __launch_bounds__(256) void convw_kernel(
    const float* __restrict__ src, _Float16* __restrict__ dst,
    int R, int Cs, int Cd, int total) {
  int idx = blockIdx.x * 256 + threadIdx.x;
  if (idx >= total) return;
  int r = idx / Cd, c = idx - r * Cd;
  float v = (r < R && c < Cs) ? src[r * Cs + c] : 0.f;
  dst[idx] = (_Float16)v;
}

// ---------------------------------------------------------------------------
// ffn_dw [1360,9] f32 -> wt f16 [2][9][680]: wt[h][ki][c] = kw[(h*680+c)*9+ki]
// ---------------------------------------------------------------------------
__global__ __launch_bounds__(256) void transw_kernel(
    const float* __restrict__ kw, _Float16* __restrict__ wt) {
  int idx = blockIdx.x * 256 + threadIdx.x;
  if (idx >= 2 * 9 * 680) return;
  int h = idx / 6120;
  int rem = idx - h * 6120;
  int ki = rem / 680;
  int c  = rem - ki * 680;
  wt[idx] = (_Float16)kw[(h * 680 + c) * 9 + ki];
}

// ---------------------------------------------------------------------------
// x2 = x + P; P is overwritten IN-PLACE with x2 (f32 [c][n]).
// LN over c -> x2nh [b][n][c] f16 (GEMM2 A-operand) via per-wave LDS transpose
// ---------------------------------------------------------------------------
__global__ __launch_bounds__(256) void ln2_kernel(
    const float* __restrict__ X, float* __restrict__ P,
    const float* __restrict__ w2, const float* __restrict__ b2,
    _Float16* __restrict__ x2nh) {
  __shared__ __align__(16) _Float16 lw[4][64 * 72];  // 72 = 64 + pad (16B-mult rows)
  int tid = threadIdx.x;
  int lane = tid & 63, w = tid >> 6;
  int loc = blockIdx.x * 256 + w * 64 + lane;   // [0, 32768) = b*4096+p
  int b = loc >> 12, p = loc & 4095;
  const float* xp = X + ((size_t)b * CDIM) * NSP + p;
  float* pp = P + ((size_t)b * CDIM) * NSP + p;
  float s = 0.f, s2 = 0.f;
  for (int c = 0; c < CDIM; ++c) {
    float v = xp[(size_t)c * NSP] + pp[(size_t)c * NSP];
    s += v; s2 += v * v;
  }
  float mu = s * (1.f / CDIM);
  float var = s2 * (1.f / CDIM) - mu * mu;
  float inv = 1.0f / sqrtf(var + 1e-5f);
  _Float16* lwp = lw[w];
  int locb = blockIdx.x * 256 + w * 64;         // wave's global location base
  for (int cc0 = 0; cc0 < CDIM; cc0 += 64) {
    for (int c = cc0; c < cc0 + 64; ++c) {
      float v = xp[(size_t)c * NSP] + pp[(size_t)c * NSP];
      pp[(size_t)c * NSP] = v;    // x2 in-place (each element touched once)
      lwp[lane * 72 + (c - cc0)] = (_Float16)((v - mu) * inv * w2[c] + b2[c]);
    }
    // wave-synchronous flush (same wave wrote lw; lgkmcnt ordering suffices)
#pragma unroll
    for (int it = 0; it < 8; ++it) {
      int m = it * 64 + lane;
      int row = m >> 3, cg = m & 7;
      half8 hv = *(const half8*)(lwp + row * 72 + cg * 8);
      *(half8*)(x2nh + ((size_t)(locb + row)) * CDIM + cc0 + cg * 8) = hv;
    }
  }
}

// ---------------------------------------------------------------------------
// Unified f16 MFMA GEMM: D[i][j] = sum_k A[i][k]*B[j][k] (+R), OutT out.
// 128x128 tile, BK=32, 4 waves (2x2 of 64x64), global_load_lds staging.
// ---------------------------------------------------------------------------
template <bool RES, typename OutT>
__global__ __launch_bounds__(256) void gemm_f16_kernel(
    const _Float16* __restrict__ A, size_t sA,
    const _Float16* __restrict__ B, size_t sB,
    const float* __restrict__ R, size_t sR,
    OutT* __restrict__ Y, size_t sY,
    int K, int ldy, int Nj) {
  __shared__ __align__(16) _Float16 As[128 * 32];
  __shared__ __align__(16) _Float16 Bs[128 * 32];
  int tid = threadIdx.x;
  int lane = tid & 63;
  int w = tid >> 6;
  int wr = w >> 1, wc = w & 1;
  int lm = lane & 15, g = lane >> 4;
  int i0 = blockIdx.y * 128;
  int j0 = blockIdx.x * 128;
  int b  = blockIdx.z;
  const _Float16* Ab = A + (size_t)b * sA;
  const _Float16* Bb = B + (size_t)b * sB;

  floatx4 acc[4][4];
#pragma unroll
  for (int mi = 0; mi < 4; ++mi)
#pragma unroll
    for (int ni = 0; ni < 4; ++ni) acc[mi][ni] = {0.f, 0.f, 0.f, 0.f};

  for (int k0 = 0; k0 < K; k0 += 32) {
    // stage 128x32 f16 A and B tiles: 512 16B-granules each, 2 per thread
#pragma unroll
    for (int jj = 0; jj < 2; ++jj) {
      int idx = jj * 256 + tid;
      int row = idx >> 2, gc = idx & 3;
      int base = idx & ~63;        // wave-chunk granule base (uniform per wave)
      gload_lds16(Ab + (size_t)(i0 + row) * K + k0 + gc * 8, As + base * 8);
      gload_lds16(Bb + (size_t)(j0 + row) * K + k0 + gc * 8, Bs + base * 8);
    }
    __syncthreads();               // compiler emits vmcnt(0) drain before barrier
    half8 ha[4], hb[4];
#pragma unroll
    for (int mi = 0; mi < 4; ++mi)
      ha[mi] = *(const half8*)(As + (wr * 64 + mi * 16 + lm) * 32 + g * 8);
#pragma unroll
    for (int ni = 0; ni < 4; ++ni)
      hb[ni] = *(const half8*)(Bs + (wc * 64 + ni * 16 + lm) * 32 + g * 8);
#pragma unroll
    for (int mi = 0; mi < 4; ++mi)
#pragma unroll
      for (int ni = 0; ni < 4; ++ni)
        acc[mi][ni] = __builtin_amdgcn_mfma_f32_16x16x32_f16(
            ha[mi], hb[ni], acc[mi][ni], 0, 0, 0);
    __syncthreads();
  }

  const float* Rb = RES ? (R + (size_t)b * sR) : nullptr;
  OutT* Yb = Y + (size_t)b * sY;
#pragma unroll
  for (int mi = 0; mi < 4; ++mi) {
#pragma unroll
    for (int ni = 0; ni < 4; ++ni) {
      int j = j0 + wc * 64 + ni * 16 + lm;
      if (j >= Nj) continue;
#pragma unroll
      for (int r = 0; r < 4; ++r) {
        int i = i0 + wr * 64 + mi * 16 + g * 4 + r;   // D row = (lane>>4)*4+r
        size_t o = (size_t)i * ldy + j;
        float v = acc[mi][ni][r];
        if (RES) v += Rb[o];
        Yb[o] = (OutT)v;
      }
    }
  }
}

// ---------------------------------------------------------------------------
// Depthwise 3x3 + exact-gelu gate, [n][c] layout, f16 t, vectorized half8.
// One thread = 8 channels at one spatial position. Weights from transposed
// f16 table wt [2][9][680] (L1-resident).
// t [b*4096][1360] f16 -> g [b*4096][704] f16 (cols 680..703 zeroed = K-pad)
// ---------------------------------------------------------------------------
__global__ __launch_bounds__(256) void dwgate_kernel(
    const _Float16* __restrict__ t, const _Float16* __restrict__ wt,
    _Float16* __restrict__ g) {
  int idx = blockIdx.x * 256 + threadIdx.x;   // [0, 32768*88)
  int grp = idx % 88;
  int bp  = idx / 88;                          // b*4096 + p
  int c0 = grp * 8;
  _Float16* gp = g + (size_t)bp * HIDP + c0;
  if (grp >= 85) {                             // K-pad columns 680..703
    half8 z = {};
    *(half8*)gp = z;
    return;
  }
  int p = bp & 4095;
  int y0 = p >> 6, x0 = p & 63;
  const _Float16* tb = t + (size_t)bp * FFN_CH;
  float accA[8], accB[8];
#pragma unroll
  for (int e = 0; e < 8; ++e) { accA[e] = 0.f; accB[e] = 0.f; }
#pragma unroll
  for (int dy = -1; dy <= 1; ++dy) {
    int yy = y0 + dy;
    if ((unsigned)yy > 63u) continue;
#pragma unroll
    for (int dx = -1; dx <= 1; ++dx) {
      int xx = x0 + dx;
      if ((unsigned)xx > 63u) continue;
      int ki = (dy + 1) * 3 + (dx + 1);
      const _Float16* tp = tb + (ptrdiff_t)(dy * 64 + dx) * FFN_CH;
      half8 va = *(const half8*)(tp + c0);
      half8 vb = *(const half8*)(tp + HID + c0);
      half8 wa = *(const half8*)(wt + ki * 680 + c0);
      half8 wb = *(const half8*)(wt + 6120 + ki * 680 + c0);
#pragma unroll
      for (int e = 0; e < 8; ++e) {
        accA[e] += (float)va[e] * (float)wa[e];
        accB[e] += (float)vb[e] * (float)wb[e];
      }
    }
  }
  half8 r;
#pragma unroll
  for (int e = 0; e < 8; ++e) {
    float a = accA[e];
    float ge = 0.5f * a * (1.f + erff(a * 0.70710678118654752440f));
    r[e] = (_Float16)(ge * accB[e]);
  }
  *(half8*)gp = r;
}

// ---------------------------------------------------------------------------
extern "C" void kernel_launch(void* const* d_in, const int* in_sizes, int n_in,
                              void* d_out, int out_size, void* d_ws, size_t ws_size,
                              hipStream_t stream) {
  const float* x         = (const float*)d_in[0];
  const float* y         = (const float*)d_in[1];
  const float* ln1x_w    = (const float*)d_in[2];
  const float* ln1x_b    = (const float*)d_in[3];
  const float* ln1y_w    = (const float*)d_in[4];
  const float* ln1y_b    = (const float*)d_in[5];
  const float* ln2_w     = (const float*)d_in[6];
  const float* ln2_b     = (const float*)d_in[7];
  const float* temperature = (const float*)d_in[8];
  const float* qkv_dw    = (const float*)d_in[9];
  const float* attn_proj_w = (const float*)d_in[10];
  const float* ffn_in_w  = (const float*)d_in[11];
  const float* ffn_dw    = (const float*)d_in[12];
  const float* ffn_out_w = (const float*)d_in[13];
  float* out = (float*)d_out;
  char* wsb = (char*)d_ws;

  // ---- compact workspace layout (bytes); total ~205 MiB ----
  // Region A [0, 32M):        xn (f32) -> P -> x2 (in-place)
  // Region B [32M, 64M):      yn (f32) -> x2n_h (f16, 16M)
  // Region C [64M, 160M):     qkv (f32, 96M) -> tbuf (f16, 87M)
  // Region D [160M, 204M):    av_h (f16, 16M) -> g_h (f16, 44M)
  // smalls   [204M, ...):     nrm, attn, wp_h, wf_h, wo_h, wt_h
  const size_t SZ_CN4 = (size_t)BATCH * CDIM * NSP * 4;          // 33,554,432
  const size_t off_A   = 0;
  const size_t off_B   = SZ_CN4;
  const size_t off_C   = 2 * SZ_CN4;
  const size_t off_D   = off_C + (size_t)BATCH * QKV_CH * NSP * 4;
  const size_t off_sm  = off_D + (size_t)BATCH * NSP * HIDP * 2; // g_h is max user of D
  const size_t off_nrm  = off_sm;
  const size_t off_attn = off_nrm + 16384;
  const size_t off_wp   = off_attn + 262144;
  const size_t off_wf   = off_wp + (size_t)CDIM * CDIM * 2;
  const size_t off_wo   = off_wf + (size_t)FFNP * CDIM * 2;
  const size_t off_wt   = off_wo + (size_t)CDIM * HIDP * 2;

  float*    xn    = (float*)(wsb + off_A);
  float*    yn    = (float*)(wsb + off_B);
  float*    qkv   = (float*)(wsb + off_C);
  _Float16* tbuf  = (_Float16*)(wsb + off_C);   // after qkv dead
  _Float16* av_h  = (_Float16*)(wsb + off_D);
  _Float16* g_h   = (_Float16*)(wsb + off_D);   // after av_h dead
  float*    P     = (float*)(wsb + off_A);      // after xn dead; becomes x2
  _Float16* x2n_h = (_Float16*)(wsb + off_B);   // after yn dead
  float*    nrm   = (float*)(wsb + off_nrm);
  float*    attn  = (float*)(wsb + off_attn);
  _Float16* wp_h  = (_Float16*)(wsb + off_wp);
  _Float16* wf_h  = (_Float16*)(wsb + off_wf);
  _Float16* wo_h  = (_Float16*)(wsb + off_wo);
  _Float16* wt_h  = (_Float16*)(wsb + off_wt);

  // ---- weight conversions (f32 -> f16, zero-padded / transposed) ----
  convw_kernel<<<(CDIM * CDIM + 255) / 256, 256, 0, stream>>>(
      attn_proj_w, wp_h, CDIM, CDIM, CDIM, CDIM * CDIM);
  convw_kernel<<<(FFNP * CDIM + 255) / 256, 256, 0, stream>>>(
      ffn_in_w, wf_h, FFN_CH, CDIM, CDIM, FFNP * CDIM);
  convw_kernel<<<(CDIM * HIDP + 255) / 256, 256, 0, stream>>>(
      ffn_out_w, wo_h, CDIM, HID, HIDP, CDIM * HIDP);
  transw_kernel<<<48, 256, 0, stream>>>(ffn_dw, wt_h);

  // ---- attention branch ----
  ln_kernel<<<BATCH * NSP / 256, 256, 0, stream>>>(x, ln1x_w, ln1x_b, xn);
  ln_kernel<<<BATCH * NSP / 256, 256, 0, stream>>>(y, ln1y_w, ln1y_b, yn);
  dwconv_qkv_kernel<<<BATCH * QKV_CH, 256, 0, stream>>>(xn, yn, qkv_dw, qkv);
  norm_kernel<<<4096, 256, 0, stream>>>(qkv, nrm);
  attn_kernel<<<BATCH * HEADS * CH, 256, 0, stream>>>(qkv, nrm, temperature, attn);
  av_kernel<<<BATCH * HEADS * (NSP / 256), 256, 0, stream>>>(qkv, attn, av_h);

  // GEMM1 (flipped): P[b][o][n] = sum_k Wproj[o][k] * av_h[b][n][k]
  {
    dim3 grid(NSP / 128, CDIM / 128, BATCH);
    gemm_f16_kernel<false, float><<<grid, 256, 0, stream>>>(
        wp_h, (size_t)0, av_h, (size_t)NSP * CDIM, nullptr, (size_t)0,
        P, (size_t)CDIM * NSP, CDIM, NSP, NSP);
  }

  // LN2 fused residual: x2 = x + P (in-place into P); x2n_h (f16 [n][c])
  ln2_kernel<<<BATCH * NSP / 256, 256, 0, stream>>>(x, P, ln2_w, ln2_b, x2n_h);

  // GEMM2: t[b][n][o] = sum_k x2n_h[b][n][k] * wf_h[o][k]  (f16 out, o<1360)
  {
    dim3 grid(FFNP / 128, NSP / 128, BATCH);
    gemm_f16_kernel<false, _Float16><<<grid, 256, 0, stream>>>(
        x2n_h, (size_t)NSP * CDIM, wf_h, (size_t)0, nullptr, (size_t)0,
        tbuf, (size_t)NSP * FFN_CH, CDIM, FFN_CH, FFN_CH);
  }

  // depthwise 3x3 + gelu gate -> g_h [b][n][704] f16 (zero-padded cols)
  dwgate_kernel<<<BATCH * NSP * 88 / 256, 256, 0, stream>>>(tbuf, wt_h, g_h);

  // GEMM3 (flipped, +residual): out[b][o][n] = x2 + sum_k wo_h[o][k]*g_h[b][n][k]
  {
    dim3 grid(NSP / 128, CDIM / 128, BATCH);
    gemm_f16_kernel<true, float><<<grid, 256, 0, stream>>>(
        wo_h, (size_t)0, g_h, (size_t)NSP * HIDP, P, (size_t)CDIM * NSP,
        out, (size_t)CDIM * NSP, HIDP, NSP, NSP);
  }
}

// Round 6
// 489.491 us; speedup vs baseline: 2.1345x; 1.2827x over previous
//
#include <hip/hip_runtime.h>
#include <hip/hip_bf16.h>
#include <math.h>

// Problem constants
#define BATCH 8
#define CDIM 256
#define HEADS 8
#define CH 32              // CDIM/HEADS
#define NSP 4096           // 64*64
#define HID 680
#define QKV_CH 768         // 3*CDIM
#define FFN_CH 1360        // 2*HID
#define HIDP 704           // HID padded to mult of 32 (K-pad for GEMM3)
#define FFNP 1408          // FFN_CH padded to mult of 128 (N-pad for GEMM2 weights)
#define GSPLIT 16          // K-splits for the QK^T Gram

typedef _Float16 half8 __attribute__((ext_vector_type(8)));
typedef float floatx4 __attribute__((ext_vector_type(4)));

// async global->LDS, 16B per lane; lds dest = wave-uniform base + lane*16
__device__ inline void gload_lds16(const _Float16* g, _Float16* l) {
  __builtin_amdgcn_global_load_lds(
      (const __attribute__((address_space(1))) unsigned int*)g,
      (__attribute__((address_space(3))) unsigned int*)l, 16, 0, 0);
}

// ---------------------------------------------------------------------------
// LayerNorm over channel dim, per spatial location. X: [B,256,4096] f32
// ---------------------------------------------------------------------------
__global__ __launch_bounds__(256) void ln_kernel(
    const float* __restrict__ X, const float* __restrict__ w,
    const float* __restrict__ bia, float* __restrict__ Y) {
  int idx = blockIdx.x * 256 + threadIdx.x;   // [0, B*4096)
  int b = idx >> 12;
  int p = idx & 4095;
  const float* xp = X + ((size_t)b * CDIM) * NSP + p;
  float s = 0.f, s2 = 0.f;
  for (int c = 0; c < CDIM; ++c) {
    float v = xp[(size_t)c * NSP];
    s += v; s2 += v * v;
  }
  float mu  = s * (1.f / CDIM);
  float var = s2 * (1.f / CDIM) - mu * mu;
  float inv = 1.0f / sqrtf(var + 1e-5f);
  float* yp = Y + ((size_t)b * CDIM) * NSP + p;
  for (int c = 0; c < CDIM; ++c) {
    float v = xp[(size_t)c * NSP];
    yp[(size_t)c * NSP] = (v - mu) * inv * w[c] + bia[c];
  }
}

// ---------------------------------------------------------------------------
// Depthwise 3x3 (SAME) -> qkv [B,768,4096] f32.
// Block per (b, src-channel-of-512): c<256 -> q from xn (1 output);
// c>=256 -> k AND v from one yn staging (yn image read once).
// ---------------------------------------------------------------------------
__global__ __launch_bounds__(256) void dwconv_qkv_kernel(
    const float* __restrict__ xn, const float* __restrict__ yn,
    const float* __restrict__ kw, float* __restrict__ out) {
  __shared__ float sm[66 * 68];       // 66 rows x 68 cols, zero border
  int bc = blockIdx.x;                // b*512 + c
  int b = bc >> 9;
  int c = bc & 511;
  bool isq = (c < 256);
  int ch = isq ? c : c - 256;
  const float* src = (isq ? xn : yn) + ((size_t)(b * CDIM + ch)) * NSP;
  int tid = threadIdx.x;
  for (int i = tid; i < 66 * 68; i += 256) sm[i] = 0.f;
  __syncthreads();
  {
    int r = tid >> 2, xq = (tid & 3) * 16;
    const float* sp = src + r * 64 + xq;
    float4 v0 = ((const float4*)sp)[0];
    float4 v1 = ((const float4*)sp)[1];
    float4 v2 = ((const float4*)sp)[2];
    float4 v3 = ((const float4*)sp)[3];
    float* lp = sm + (r + 1) * 68 + 1 + xq;
    lp[0]=v0.x; lp[1]=v0.y; lp[2]=v0.z;  lp[3]=v0.w;
    lp[4]=v1.x; lp[5]=v1.y; lp[6]=v1.z;  lp[7]=v1.w;
    lp[8]=v2.x; lp[9]=v2.y; lp[10]=v2.z; lp[11]=v2.w;
    lp[12]=v3.x;lp[13]=v3.y;lp[14]=v3.z; lp[15]=v3.w;
  }
  __syncthreads();
  int r = tid >> 2, xs = (tid & 3) * 16;
  float row0[18], row1[18], row2[18];
  {
    const float* q0 = sm + (r + 0) * 68 + xs;
    const float* q1 = sm + (r + 1) * 68 + xs;
    const float* q2 = sm + (r + 2) * 68 + xs;
#pragma unroll
    for (int j = 0; j < 4; ++j) {
      float4 a0 = *(const float4*)(q0 + j * 4);
      float4 a1 = *(const float4*)(q1 + j * 4);
      float4 a2 = *(const float4*)(q2 + j * 4);
      row0[j*4+0]=a0.x; row0[j*4+1]=a0.y; row0[j*4+2]=a0.z; row0[j*4+3]=a0.w;
      row1[j*4+0]=a1.x; row1[j*4+1]=a1.y; row1[j*4+2]=a1.z; row1[j*4+3]=a1.w;
      row2[j*4+0]=a2.x; row2[j*4+1]=a2.y; row2[j*4+2]=a2.z; row2[j*4+3]=a2.w;
    }
    row0[16]=q0[16]; row0[17]=q0[17];
    row1[16]=q1[16]; row1[17]=q1[17];
    row2[16]=q2[16]; row2[17]=q2[17];
  }
  int nouts = isq ? 1 : 2;
  int kcs[2];
  kcs[0] = isq ? c : (256 + ch);
  kcs[1] = 512 + ch;
  for (int oi = 0; oi < nouts; ++oi) {
    int kc = kcs[oi];
    float k9[9];
#pragma unroll
    for (int i = 0; i < 9; ++i) k9[i] = kw[kc * 9 + i];
    float acc[16];
#pragma unroll
    for (int i = 0; i < 16; ++i) {
      acc[i] = row0[i]*k9[0] + row0[i+1]*k9[1] + row0[i+2]*k9[2]
             + row1[i]*k9[3] + row1[i+1]*k9[4] + row1[i+2]*k9[5]
             + row2[i]*k9[6] + row2[i+1]*k9[7] + row2[i+2]*k9[8];
    }
    float* op = out + ((size_t)b * QKV_CH + kc) * NSP + r * 64 + xs;
#pragma unroll
    for (int j = 0; j < 4; ++j)
      ((float4*)op)[j] = make_float4(acc[j*4+0], acc[j*4+1], acc[j*4+2], acc[j*4+3]);
  }
}

// ---------------------------------------------------------------------------
// Partial QK^T Gram via MFMA + partial q/k sq-norms.
// Block = (bh, split): stages q/k [32][256] f32->f16 in LDS, accumulates
// f32 ssq during staging. Wave w computes quadrant (w>>1, w&1).
// Gp[bh][split][32*32], Np[bh][split][64] (q ssq 0..31, k ssq 32..63)
// ---------------------------------------------------------------------------
__global__ __launch_bounds__(256) void attn_gram_kernel(
    const float* __restrict__ qkv, float* __restrict__ Gp,
    float* __restrict__ Np) {
  __shared__ __align__(16) _Float16 lq[32 * 264];
  __shared__ __align__(16) _Float16 lk[32 * 264];
  int bi = blockIdx.x;        // bh*GSPLIT + split
  int split = bi & (GSPLIT - 1);
  int bh = bi / GSPLIT;
  int b = bh >> 3, h = bh & 7;
  int tid = threadIdx.x;
  int row = tid >> 3, cg = (tid & 7) * 32;
  int n0 = split * (NSP / GSPLIT);            // 256 cols
  const float* qp = qkv + ((size_t)(b * QKV_CH) + h * CH + row) * NSP + n0 + cg;
  const float* kp = qkv + ((size_t)(b * QKV_CH) + 256 + h * CH + row) * NSP + n0 + cg;
  float sq = 0.f, sk = 0.f;
  _Float16* lqd = lq + row * 264 + cg;
  _Float16* lkd = lk + row * 264 + cg;
#pragma unroll
  for (int j = 0; j < 4; ++j) {
    float4 a0 = *(const float4*)(qp + j * 8);
    float4 a1 = *(const float4*)(qp + j * 8 + 4);
    sq += a0.x*a0.x + a0.y*a0.y + a0.z*a0.z + a0.w*a0.w
        + a1.x*a1.x + a1.y*a1.y + a1.z*a1.z + a1.w*a1.w;
    half8 hv = {(_Float16)a0.x,(_Float16)a0.y,(_Float16)a0.z,(_Float16)a0.w,
                (_Float16)a1.x,(_Float16)a1.y,(_Float16)a1.z,(_Float16)a1.w};
    *(half8*)(lqd + j * 8) = hv;
    float4 b0 = *(const float4*)(kp + j * 8);
    float4 b1 = *(const float4*)(kp + j * 8 + 4);
    sk += b0.x*b0.x + b0.y*b0.y + b0.z*b0.z + b0.w*b0.w
        + b1.x*b1.x + b1.y*b1.y + b1.z*b1.z + b1.w*b1.w;
    half8 hw = {(_Float16)b0.x,(_Float16)b0.y,(_Float16)b0.z,(_Float16)b0.w,
                (_Float16)b1.x,(_Float16)b1.y,(_Float16)b1.z,(_Float16)b1.w};
    *(half8*)(lkd + j * 8) = hw;
  }
  __syncthreads();
  int lane = tid & 63, w = tid >> 6;
  int wr = w >> 1, wc = w & 1;
  int lm = lane & 15, g = lane >> 4;
  floatx4 acc = {0.f, 0.f, 0.f, 0.f};
#pragma unroll
  for (int kk = 0; kk < 8; ++kk) {
    half8 av = *(const half8*)(lq + (wr * 16 + lm) * 264 + kk * 32 + g * 8);
    half8 bv = *(const half8*)(lk + (wc * 16 + lm) * 264 + kk * 32 + g * 8);
    acc = __builtin_amdgcn_mfma_f32_16x16x32_f16(av, bv, acc, 0, 0, 0);
  }
  // partial norms: reduce over the 8-thread group sharing a row
  sq += __shfl_xor(sq, 1); sq += __shfl_xor(sq, 2); sq += __shfl_xor(sq, 4);
  sk += __shfl_xor(sk, 1); sk += __shfl_xor(sk, 2); sk += __shfl_xor(sk, 4);
  if ((tid & 7) == 0) {
    float* np = Np + ((size_t)bh * GSPLIT + split) * 64;
    np[row] = sq;
    np[32 + row] = sk;
  }
  float* gp = Gp + ((size_t)bh * GSPLIT + split) * 1024;
#pragma unroll
  for (int r = 0; r < 4; ++r) {
    int i = wr * 16 + g * 4 + r, j = wc * 16 + lm;
    gp[i * 32 + j] = acc[r];
  }
}

// ---------------------------------------------------------------------------
// Reduce partial Gram/norms, apply 1/(|q||k|)*temp, softmax -> attn[bh][32][32]
// ---------------------------------------------------------------------------
__global__ __launch_bounds__(256) void attn_softmax_kernel(
    const float* __restrict__ Gp, const float* __restrict__ Np,
    const float* __restrict__ temp, float* __restrict__ attn) {
  __shared__ float G[1024];
  __shared__ float qn[32], kn[32];
  int bh = blockIdx.x;
  int tid = threadIdx.x;
  const float* gp = Gp + (size_t)bh * GSPLIT * 1024;
#pragma unroll
  for (int e = tid; e < 1024; e += 256) {
    float s = 0.f;
#pragma unroll
    for (int sp = 0; sp < GSPLIT; ++sp) s += gp[sp * 1024 + e];
    G[e] = s;
  }
  if (tid < 64) {
    const float* np = Np + (size_t)bh * GSPLIT * 64;
    float s = 0.f;
#pragma unroll
    for (int sp = 0; sp < GSPLIT; ++sp) s += np[sp * 64 + tid];
    float nv = fmaxf(sqrtf(s), 1e-12f);
    if (tid < 32) qn[tid] = nv; else kn[tid - 32] = nv;
  }
  __syncthreads();
  if (tid < 32) {
    int c = tid;
    float t = temp[bh & 7];
    float iq = 1.f / qn[c];
    float vals[32];
    float m = -1e30f;
#pragma unroll
    for (int d = 0; d < 32; ++d) {
      float v = G[c * 32 + d] * iq / kn[d] * t;
      vals[d] = v; m = fmaxf(m, v);
    }
    float ss = 0.f;
#pragma unroll
    for (int d = 0; d < 32; ++d) { float e = expf(vals[d] - m); vals[d] = e; ss += e; }
    float inv = 1.f / ss;
#pragma unroll
    for (int d = 0; d < 32; ++d)
      attn[(size_t)bh * 1024 + c * 32 + d] = vals[d] * inv;
  }
}

// ---------------------------------------------------------------------------
// avout_h[b][n][c] (f16, [n][c] layout!) = sum_d attn[b,h,c,d] * v[b,h,d,n]
// ---------------------------------------------------------------------------
__global__ __launch_bounds__(256) void av_kernel(
    const float* __restrict__ qkv, const float* __restrict__ attn,
    _Float16* __restrict__ outh) {
  __shared__ float a_s[1024];
  __shared__ float tr[256 * 33];   // +1 pad word per row -> conflict-free
  int bi = blockIdx.x;           // (b*8+h)*16 + chunk
  int chunk = bi & 15;
  int h = (bi >> 4) & 7;
  int b = bi >> 7;
  int tid = threadIdx.x;
  for (int j = tid; j < 1024; j += 256)
    a_s[j] = attn[((size_t)(b * 8 + h)) * 1024 + j];
  __syncthreads();
  int n = chunk * 256 + tid;
  const float* vbase = qkv + ((size_t)(b * QKV_CH + 512 + h * CH)) * NSP + n;
  float acc[32];
#pragma unroll
  for (int c = 0; c < 32; ++c) acc[c] = 0.f;
#pragma unroll 4
  for (int d = 0; d < 32; ++d) {
    float vv = vbase[(size_t)d * NSP];
#pragma unroll
    for (int c = 0; c < 32; ++c) acc[c] += a_s[c * 32 + d] * vv;
  }
#pragma unroll
  for (int c = 0; c < 32; ++c) tr[tid * 33 + c] = acc[c];
  __syncthreads();
#pragma unroll
  for (int it = 0; it < 4; ++it) {
    int gi = it * 256 + tid;
    int row = gi >> 2, gc = gi & 3;
    half8 hv;
#pragma unroll
    for (int e = 0; e < 8; ++e) hv[e] = (_Float16)tr[row * 33 + gc * 8 + e];
    *(half8*)(outh + ((size_t)(b * NSP + chunk * 256 + row)) * CDIM + h * CH + gc * 8) = hv;
  }
}

// ---------------------------------------------------------------------------
// Weight f32 -> f16 with zero padding. dst [Rd][Cd], src [R][Cs]
// ---------------------------------------------------------------------------
__global__ __launch_bounds__(256) void convw_kernel(
    const float* __restrict__ src, _Float16* __restrict__ dst,
    int R, int Cs, int Cd, int total) {
  int idx = blockIdx.x * 256 + threadIdx.x;
  if (idx >= total) return;
  int r = idx / Cd, c = idx - r * Cd;
  float v = (r < R && c < Cs) ? src[r * Cs + c] : 0.f;
  dst[idx] = (_Float16)v;
}

// ---------------------------------------------------------------------------
// ffn_dw [1360,9] f32 -> wt f16 [2][9][680]: wt[h][ki][c] = kw[(h*680+c)*9+ki]
// ---------------------------------------------------------------------------
__global__ __launch_bounds__(256) void transw_kernel(
    const float* __restrict__ kw, _Float16* __restrict__ wt) {
  int idx = blockIdx.x * 256 + threadIdx.x;
  if (idx >= 2 * 9 * 680) return;
  int h = idx / 6120;
  int rem = idx - h * 6120;
  int ki = rem / 680;
  int c  = rem - ki * 680;
  wt[idx] = (_Float16)kw[(h * 680 + c) * 9 + ki];
}

// ---------------------------------------------------------------------------
// x2 = x + P; P is overwritten IN-PLACE with x2 (f32 [c][n]).
// LN over c -> x2nh [b][n][c] f16 via per-wave LDS transpose
// ---------------------------------------------------------------------------
__global__ __launch_bounds__(256) void ln2_kernel(
    const float* __restrict__ X, float* __restrict__ P,
    const float* __restrict__ w2, const float* __restrict__ b2,
    _Float16* __restrict__ x2nh) {
  __shared__ __align__(16) _Float16 lw[4][64 * 72];  // 72 = 64 + pad
  int tid = threadIdx.x;
  int lane = tid & 63, w = tid >> 6;
  int loc = blockIdx.x * 256 + w * 64 + lane;   // [0, 32768) = b*4096+p
  int b = loc >> 12, p = loc & 4095;
  const float* xp = X + ((size_t)b * CDIM) * NSP + p;
  float* pp = P + ((size_t)b * CDIM) * NSP + p;
  float s = 0.f, s2 = 0.f;
  for (int c = 0; c < CDIM; ++c) {
    float v = xp[(size_t)c * NSP] + pp[(size_t)c * NSP];
    s += v; s2 += v * v;
  }
  float mu = s * (1.f / CDIM);
  float var = s2 * (1.f / CDIM) - mu * mu;
  float inv = 1.0f / sqrtf(var + 1e-5f);
  _Float16* lwp = lw[w];
  int locb = blockIdx.x * 256 + w * 64;
  for (int cc0 = 0; cc0 < CDIM; cc0 += 64) {
    for (int c = cc0; c < cc0 + 64; ++c) {
      float v = xp[(size_t)c * NSP] + pp[(size_t)c * NSP];
      pp[(size_t)c * NSP] = v;    // x2 in-place
      lwp[lane * 72 + (c - cc0)] = (_Float16)((v - mu) * inv * w2[c] + b2[c]);
    }
#pragma unroll
    for (int it = 0; it < 8; ++it) {
      int m = it * 64 + lane;
      int row = m >> 3, cg = m & 7;
      half8 hv = *(const half8*)(lwp + row * 72 + cg * 8);
      *(half8*)(x2nh + ((size_t)(locb + row)) * CDIM + cc0 + cg * 8) = hv;
    }
  }
}

// ---------------------------------------------------------------------------
// Unified f16 MFMA GEMM: D[i][j] = sum_k A[i][k]*B[j][k] (+R), OutT out.
// 128x128 tile, BK=32, 4 waves (2x2 of 64x64), global_load_lds staging.
// ---------------------------------------------------------------------------
template <bool RES, typename OutT>
__global__ __launch_bounds__(256) void gemm_f16_kernel(
    const _Float16* __restrict__ A, size_t sA,
    const _Float16* __restrict__ B, size_t sB,
    const float* __restrict__ R, size_t sR,
    OutT* __restrict__ Y, size_t sY,
    int K, int ldy, int Nj) {
  __shared__ __align__(16) _Float16 As[128 * 32];
  __shared__ __align__(16) _Float16 Bs[128 * 32];
  int tid = threadIdx.x;
  int lane = tid & 63;
  int w = tid >> 6;
  int wr = w >> 1, wc = w & 1;
  int lm = lane & 15, g = lane >> 4;
  int i0 = blockIdx.y * 128;
  int j0 = blockIdx.x * 128;
  int b  = blockIdx.z;
  const _Float16* Ab = A + (size_t)b * sA;
  const _Float16* Bb = B + (size_t)b * sB;

  floatx4 acc[4][4];
#pragma unroll
  for (int mi = 0; mi < 4; ++mi)
#pragma unroll
    for (int ni = 0; ni < 4; ++ni) acc[mi][ni] = {0.f, 0.f, 0.f, 0.f};

  for (int k0 = 0; k0 < K; k0 += 32) {
#pragma unroll
    for (int jj = 0; jj < 2; ++jj) {
      int idx = jj * 256 + tid;
      int row = idx >> 2, gc = idx & 3;
      int base = idx & ~63;        // wave-chunk granule base (uniform per wave)
      gload_lds16(Ab + (size_t)(i0 + row) * K + k0 + gc * 8, As + base * 8);
      gload_lds16(Bb + (size_t)(j0 + row) * K + k0 + gc * 8, Bs + base * 8);
    }
    __syncthreads();
    half8 ha[4], hb[4];
#pragma unroll
    for (int mi = 0; mi < 4; ++mi)
      ha[mi] = *(const half8*)(As + (wr * 64 + mi * 16 + lm) * 32 + g * 8);
#pragma unroll
    for (int ni = 0; ni < 4; ++ni)
      hb[ni] = *(const half8*)(Bs + (wc * 64 + ni * 16 + lm) * 32 + g * 8);
#pragma unroll
    for (int mi = 0; mi < 4; ++mi)
#pragma unroll
      for (int ni = 0; ni < 4; ++ni)
        acc[mi][ni] = __builtin_amdgcn_mfma_f32_16x16x32_f16(
            ha[mi], hb[ni], acc[mi][ni], 0, 0, 0);
    __syncthreads();
  }

  const float* Rb = RES ? (R + (size_t)b * sR) : nullptr;
  OutT* Yb = Y + (size_t)b * sY;
#pragma unroll
  for (int mi = 0; mi < 4; ++mi) {
#pragma unroll
    for (int ni = 0; ni < 4; ++ni) {
      int j = j0 + wc * 64 + ni * 16 + lm;
      if (j >= Nj) continue;
#pragma unroll
      for (int r = 0; r < 4; ++r) {
        int i = i0 + wr * 64 + mi * 16 + g * 4 + r;
        size_t o = (size_t)i * ldy + j;
        float v = acc[mi][ni][r];
        if (RES) v += Rb[o];
        Yb[o] = (OutT)v;
      }
    }
  }
}

// ---------------------------------------------------------------------------
// Depthwise 3x3 + exact-gelu gate, [n][c] layout, f16, vectorized half8.
// ---------------------------------------------------------------------------
__global__ __launch_bounds__(256) void dwgate_kernel(
    const _Float16* __restrict__ t, const _Float16* __restrict__ wt,
    _Float16* __restrict__ g) {
  int idx = blockIdx.x * 256 + threadIdx.x;   // [0, 32768*88)
  int grp = idx % 88;
  int bp  = idx / 88;                          // b*4096 + p
  int c0 = grp * 8;
  _Float16* gp = g + (size_t)bp * HIDP + c0;
  if (grp >= 85) {                             // K-pad columns 680..703
    half8 z = {};
    *(half8*)gp = z;
    return;
  }
  int p = bp & 4095;
  int y0 = p >> 6, x0 = p & 63;
  const _Float16* tb = t + (size_t)bp * FFN_CH;
  float accA[8], accB[8];
#pragma unroll
  for (int e = 0; e < 8; ++e) { accA[e] = 0.f; accB[e] = 0.f; }
#pragma unroll
  for (int dy = -1; dy <= 1; ++dy) {
    int yy = y0 + dy;
    if ((unsigned)yy > 63u) continue;
#pragma unroll
    for (int dx = -1; dx <= 1; ++dx) {
      int xx = x0 + dx;
      if ((unsigned)xx > 63u) continue;
      int ki = (dy + 1) * 3 + (dx + 1);
      const _Float16* tp = tb + (ptrdiff_t)(dy * 64 + dx) * FFN_CH;
      half8 va = *(const half8*)(tp + c0);
      half8 vb = *(const half8*)(tp + HID + c0);
      half8 wa = *(const half8*)(wt + ki * 680 + c0);
      half8 wb = *(const half8*)(wt + 6120 + ki * 680 + c0);
#pragma unroll
      for (int e = 0; e < 8; ++e) {
        accA[e] += (float)va[e] * (float)wa[e];
        accB[e] += (float)vb[e] * (float)wb[e];
      }
    }
  }
  half8 r;
#pragma unroll
  for (int e = 0; e < 8; ++e) {
    float a = accA[e];
    float ge = 0.5f * a * (1.f + erff(a * 0.70710678118654752440f));
    r[e] = (_Float16)(ge * accB[e]);
  }
  *(half8*)gp = r;
}

// ---------------------------------------------------------------------------
extern "C" void kernel_launch(void* const* d_in, const int* in_sizes, int n_in,
                              void* d_out, int out_size, void* d_ws, size_t ws_size,
                              hipStream_t stream) {
  const float* x         = (const float*)d_in[0];
  const float* y         = (const float*)d_in[1];
  const float* ln1x_w    = (const float*)d_in[2];
  const float* ln1x_b    = (const float*)d_in[3];
  const float* ln1y_w    = (const float*)d_in[4];
  const float* ln1y_b    = (const float*)d_in[5];
  const float* ln2_w     = (const float*)d_in[6];
  const float* ln2_b     = (const float*)d_in[7];
  const float* temperature = (const float*)d_in[8];
  const float* qkv_dw    = (const float*)d_in[9];
  const float* attn_proj_w = (const float*)d_in[10];
  const float* ffn_in_w  = (const float*)d_in[11];
  const float* ffn_dw    = (const float*)d_in[12];
  const float* ffn_out_w = (const float*)d_in[13];
  float* out = (float*)d_out;
  char* wsb = (char*)d_ws;

  // ---- workspace layout (bytes); same footprint as R4 (~206 MiB) ----
  // Region A [0, 32M):    xn (f32) -> P -> x2 (in-place)
  // Region B [32M, 64M):  yn (f32) -> x2n_h (f16)
  // Region C [64M, 160M): qkv (f32, 96M) -> tbuf (f16, 85M)
  // Region D [160M, 204M): av_h (f16, 16M) + Gp/Np @ +20M -> g_h (f16, 44M)
  // smalls   [204M, ...):  attn, wp_h, wf_h, wo_h, wt_h
  const size_t SZ_CN4 = (size_t)BATCH * CDIM * NSP * 4;          // 33,554,432
  const size_t off_A   = 0;
  const size_t off_B   = SZ_CN4;
  const size_t off_C   = 2 * SZ_CN4;
  const size_t off_D   = off_C + (size_t)BATCH * QKV_CH * NSP * 4;
  const size_t off_gp  = off_D + 20u * 1024 * 1024;              // 4 MB (dead before g_h)
  const size_t off_np  = off_gp + (size_t)64 * GSPLIT * 1024 * 4;
  const size_t off_sm  = off_D + (size_t)BATCH * NSP * HIDP * 2; // g_h extent
  const size_t off_attn = off_sm;
  const size_t off_wp   = off_attn + 262144;
  const size_t off_wf   = off_wp + (size_t)CDIM * CDIM * 2;
  const size_t off_wo   = off_wf + (size_t)FFNP * CDIM * 2;
  const size_t off_wt   = off_wo + (size_t)CDIM * HIDP * 2;

  float*    xn    = (float*)(wsb + off_A);
  float*    yn    = (float*)(wsb + off_B);
  float*    qkv   = (float*)(wsb + off_C);
  _Float16* tbuf  = (_Float16*)(wsb + off_C);   // after qkv dead
  _Float16* av_h  = (_Float16*)(wsb + off_D);
  _Float16* g_h   = (_Float16*)(wsb + off_D);   // after av_h/Gp/Np dead
  float*    Gp    = (float*)(wsb + off_gp);
  float*    Np    = (float*)(wsb + off_np);
  float*    P     = (float*)(wsb + off_A);      // after xn dead; becomes x2
  _Float16* x2n_h = (_Float16*)(wsb + off_B);   // after yn dead
  float*    attn  = (float*)(wsb + off_attn);
  _Float16* wp_h  = (_Float16*)(wsb + off_wp);
  _Float16* wf_h  = (_Float16*)(wsb + off_wf);
  _Float16* wo_h  = (_Float16*)(wsb + off_wo);
  _Float16* wt_h  = (_Float16*)(wsb + off_wt);

  // ---- weight conversions ----
  convw_kernel<<<(CDIM * CDIM + 255) / 256, 256, 0, stream>>>(
      attn_proj_w, wp_h, CDIM, CDIM, CDIM, CDIM * CDIM);
  convw_kernel<<<(FFNP * CDIM + 255) / 256, 256, 0, stream>>>(
      ffn_in_w, wf_h, FFN_CH, CDIM, CDIM, FFNP * CDIM);
  convw_kernel<<<(CDIM * HIDP + 255) / 256, 256, 0, stream>>>(
      ffn_out_w, wo_h, CDIM, HID, HIDP, CDIM * HIDP);
  transw_kernel<<<48, 256, 0, stream>>>(ffn_dw, wt_h);

  // ---- attention branch ----
  ln_kernel<<<BATCH * NSP / 256, 256, 0, stream>>>(x, ln1x_w, ln1x_b, xn);
  ln_kernel<<<BATCH * NSP / 256, 256, 0, stream>>>(y, ln1y_w, ln1y_b, yn);
  dwconv_qkv_kernel<<<BATCH * 512, 256, 0, stream>>>(xn, yn, qkv_dw, qkv);
  attn_gram_kernel<<<BATCH * HEADS * GSPLIT, 256, 0, stream>>>(qkv, Gp, Np);
  attn_softmax_kernel<<<BATCH * HEADS, 256, 0, stream>>>(Gp, Np, temperature, attn);
  av_kernel<<<BATCH * HEADS * (NSP / 256), 256, 0, stream>>>(qkv, attn, av_h);

  // GEMM1 (flipped): P[b][o][n] = sum_k Wproj[o][k] * av_h[b][n][k]
  {
    dim3 grid(NSP / 128, CDIM / 128, BATCH);
    gemm_f16_kernel<false, float><<<grid, 256, 0, stream>>>(
        wp_h, (size_t)0, av_h, (size_t)NSP * CDIM, nullptr, (size_t)0,
        P, (size_t)CDIM * NSP, CDIM, NSP, NSP);
  }

  // LN2 fused residual: x2 = x + P (in-place into P); x2n_h (f16 [n][c])
  ln2_kernel<<<BATCH * NSP / 256, 256, 0, stream>>>(x, P, ln2_w, ln2_b, x2n_h);

  // GEMM2: t[b][n][o] = sum_k x2n_h[b][n][k] * wf_h[o][k]  (f16 out)
  {
    dim3 grid(FFNP / 128, NSP / 128, BATCH);
    gemm_f16_kernel<false, _Float16><<<grid, 256, 0, stream>>>(
        x2n_h, (size_t)NSP * CDIM, wf_h, (size_t)0, nullptr, (size_t)0,
        tbuf, (size_t)NSP * FFN_CH, CDIM, FFN_CH, FFN_CH);
  }

  // depthwise 3x3 + gelu gate -> g_h [b][n][704] f16
  dwgate_kernel<<<BATCH * NSP * 88 / 256, 256, 0, stream>>>(tbuf, wt_h, g_h);

  // GEMM3 (flipped, +residual): out = x2 + ffn_out(g)
  {
    dim3 grid(NSP / 128, CDIM / 128, BATCH);
    gemm_f16_kernel<true, float><<<grid, 256, 0, stream>>>(
        wo_h, (size_t)0, g_h, (size_t)NSP * HIDP, P, (size_t)CDIM * NSP,
        out, (size_t)CDIM * NSP, HIDP, NSP, NSP);
  }
}

// Round 7
// 467.573 us; speedup vs baseline: 2.2345x; 1.0469x over previous
//
#include <hip/hip_runtime.h>
#include <hip/hip_bf16.h>
#include <math.h>

// Problem constants
#define BATCH 8
#define CDIM 256
#define HEADS 8
#define CH 32              // CDIM/HEADS
#define NSP 4096           // 64*64
#define HID 680
#define QKV_CH 768         // 3*CDIM
#define FFN_CH 1360        // 2*HID
#define HIDP 704           // HID padded to mult of 32 (K-pad for GEMM3)
#define FFNP 1408          // FFN_CH padded to mult of 128 (N-pad for GEMM2 weights)
#define GSPLIT 16          // K-splits for the QK^T Gram

typedef _Float16 half8 __attribute__((ext_vector_type(8)));
typedef float floatx4 __attribute__((ext_vector_type(4)));

// async global->LDS, 16B per lane; lds dest = wave-uniform base + lane*16
__device__ inline void gload_lds16(const _Float16* g, _Float16* l) {
  __builtin_amdgcn_global_load_lds(
      (const __attribute__((address_space(1))) unsigned int*)g,
      (__attribute__((address_space(3))) unsigned int*)l, 16, 0, 0);
}

// ---------------------------------------------------------------------------
// LayerNorm over channel dim, per spatial location. X: [B,256,4096] f32
// ---------------------------------------------------------------------------
__global__ __launch_bounds__(256) void ln_kernel(
    const float* __restrict__ X, const float* __restrict__ w,
    const float* __restrict__ bia, float* __restrict__ Y) {
  int idx = blockIdx.x * 256 + threadIdx.x;   // [0, B*4096)
  int b = idx >> 12;
  int p = idx & 4095;
  const float* xp = X + ((size_t)b * CDIM) * NSP + p;
  float s = 0.f, s2 = 0.f;
  for (int c = 0; c < CDIM; ++c) {
    float v = xp[(size_t)c * NSP];
    s += v; s2 += v * v;
  }
  float mu  = s * (1.f / CDIM);
  float var = s2 * (1.f / CDIM) - mu * mu;
  float inv = 1.0f / sqrtf(var + 1e-5f);
  float* yp = Y + ((size_t)b * CDIM) * NSP + p;
  for (int c = 0; c < CDIM; ++c) {
    float v = xp[(size_t)c * NSP];
    yp[(size_t)c * NSP] = (v - mu) * inv * w[c] + bia[c];
  }
}

// ---------------------------------------------------------------------------
// Depthwise 3x3 (SAME) -> qkv [B,768,4096] f32.
// Block per (b, src-channel-of-512): c<256 -> q from xn (1 output);
// c>=256 -> k AND v from one yn staging (yn image read once).
// ---------------------------------------------------------------------------
__global__ __launch_bounds__(256) void dwconv_qkv_kernel(
    const float* __restrict__ xn, const float* __restrict__ yn,
    const float* __restrict__ kw, float* __restrict__ out) {
  __shared__ float sm[66 * 68];       // 66 rows x 68 cols, zero border
  int bc = blockIdx.x;                // b*512 + c
  int b = bc >> 9;
  int c = bc & 511;
  bool isq = (c < 256);
  int ch = isq ? c : c - 256;
  const float* src = (isq ? xn : yn) + ((size_t)(b * CDIM + ch)) * NSP;
  int tid = threadIdx.x;
  for (int i = tid; i < 66 * 68; i += 256) sm[i] = 0.f;
  __syncthreads();
  {
    int r = tid >> 2, xq = (tid & 3) * 16;
    const float* sp = src + r * 64 + xq;
    float4 v0 = ((const float4*)sp)[0];
    float4 v1 = ((const float4*)sp)[1];
    float4 v2 = ((const float4*)sp)[2];
    float4 v3 = ((const float4*)sp)[3];
    float* lp = sm + (r + 1) * 68 + 1 + xq;
    lp[0]=v0.x; lp[1]=v0.y; lp[2]=v0.z;  lp[3]=v0.w;
    lp[4]=v1.x; lp[5]=v1.y; lp[6]=v1.z;  lp[7]=v1.w;
    lp[8]=v2.x; lp[9]=v2.y; lp[10]=v2.z; lp[11]=v2.w;
    lp[12]=v3.x;lp[13]=v3.y;lp[14]=v3.z; lp[15]=v3.w;
  }
  __syncthreads();
  int r = tid >> 2, xs = (tid & 3) * 16;
  float row0[18], row1[18], row2[18];
  {
    const float* q0 = sm + (r + 0) * 68 + xs;
    const float* q1 = sm + (r + 1) * 68 + xs;
    const float* q2 = sm + (r + 2) * 68 + xs;
#pragma unroll
    for (int j = 0; j < 4; ++j) {
      float4 a0 = *(const float4*)(q0 + j * 4);
      float4 a1 = *(const float4*)(q1 + j * 4);
      float4 a2 = *(const float4*)(q2 + j * 4);
      row0[j*4+0]=a0.x; row0[j*4+1]=a0.y; row0[j*4+2]=a0.z; row0[j*4+3]=a0.w;
      row1[j*4+0]=a1.x; row1[j*4+1]=a1.y; row1[j*4+2]=a1.z; row1[j*4+3]=a1.w;
      row2[j*4+0]=a2.x; row2[j*4+1]=a2.y; row2[j*4+2]=a2.z; row2[j*4+3]=a2.w;
    }
    row0[16]=q0[16]; row0[17]=q0[17];
    row1[16]=q1[16]; row1[17]=q1[17];
    row2[16]=q2[16]; row2[17]=q2[17];
  }
  int nouts = isq ? 1 : 2;
  int kcs[2];
  kcs[0] = isq ? c : (256 + ch);
  kcs[1] = 512 + ch;
  for (int oi = 0; oi < nouts; ++oi) {
    int kc = kcs[oi];
    float k9[9];
#pragma unroll
    for (int i = 0; i < 9; ++i) k9[i] = kw[kc * 9 + i];
    float acc[16];
#pragma unroll
    for (int i = 0; i < 16; ++i) {
      acc[i] = row0[i]*k9[0] + row0[i+1]*k9[1] + row0[i+2]*k9[2]
             + row1[i]*k9[3] + row1[i+1]*k9[4] + row1[i+2]*k9[5]
             + row2[i]*k9[6] + row2[i+1]*k9[7] + row2[i+2]*k9[8];
    }
    float* op = out + ((size_t)b * QKV_CH + kc) * NSP + r * 64 + xs;
#pragma unroll
    for (int j = 0; j < 4; ++j)
      ((float4*)op)[j] = make_float4(acc[j*4+0], acc[j*4+1], acc[j*4+2], acc[j*4+3]);
  }
}

// ---------------------------------------------------------------------------
// Partial QK^T Gram via MFMA + partial q/k sq-norms.
// ---------------------------------------------------------------------------
__global__ __launch_bounds__(256) void attn_gram_kernel(
    const float* __restrict__ qkv, float* __restrict__ Gp,
    float* __restrict__ Np) {
  __shared__ __align__(16) _Float16 lq[32 * 264];
  __shared__ __align__(16) _Float16 lk[32 * 264];
  int bi = blockIdx.x;        // bh*GSPLIT + split
  int split = bi & (GSPLIT - 1);
  int bh = bi / GSPLIT;
  int b = bh >> 3, h = bh & 7;
  int tid = threadIdx.x;
  int row = tid >> 3, cg = (tid & 7) * 32;
  int n0 = split * (NSP / GSPLIT);            // 256 cols
  const float* qp = qkv + ((size_t)(b * QKV_CH) + h * CH + row) * NSP + n0 + cg;
  const float* kp = qkv + ((size_t)(b * QKV_CH) + 256 + h * CH + row) * NSP + n0 + cg;
  float sq = 0.f, sk = 0.f;
  _Float16* lqd = lq + row * 264 + cg;
  _Float16* lkd = lk + row * 264 + cg;
#pragma unroll
  for (int j = 0; j < 4; ++j) {
    float4 a0 = *(const float4*)(qp + j * 8);
    float4 a1 = *(const float4*)(qp + j * 8 + 4);
    sq += a0.x*a0.x + a0.y*a0.y + a0.z*a0.z + a0.w*a0.w
        + a1.x*a1.x + a1.y*a1.y + a1.z*a1.z + a1.w*a1.w;
    half8 hv = {(_Float16)a0.x,(_Float16)a0.y,(_Float16)a0.z,(_Float16)a0.w,
                (_Float16)a1.x,(_Float16)a1.y,(_Float16)a1.z,(_Float16)a1.w};
    *(half8*)(lqd + j * 8) = hv;
    float4 b0 = *(const float4*)(kp + j * 8);
    float4 b1 = *(const float4*)(kp + j * 8 + 4);
    sk += b0.x*b0.x + b0.y*b0.y + b0.z*b0.z + b0.w*b0.w
        + b1.x*b1.x + b1.y*b1.y + b1.z*b1.z + b1.w*b1.w;
    half8 hw = {(_Float16)b0.x,(_Float16)b0.y,(_Float16)b0.z,(_Float16)b0.w,
                (_Float16)b1.x,(_Float16)b1.y,(_Float16)b1.z,(_Float16)b1.w};
    *(half8*)(lkd + j * 8) = hw;
  }
  __syncthreads();
  int lane = tid & 63, w = tid >> 6;
  int wr = w >> 1, wc = w & 1;
  int lm = lane & 15, g = lane >> 4;
  floatx4 acc = {0.f, 0.f, 0.f, 0.f};
#pragma unroll
  for (int kk = 0; kk < 8; ++kk) {
    half8 av = *(const half8*)(lq + (wr * 16 + lm) * 264 + kk * 32 + g * 8);
    half8 bv = *(const half8*)(lk + (wc * 16 + lm) * 264 + kk * 32 + g * 8);
    acc = __builtin_amdgcn_mfma_f32_16x16x32_f16(av, bv, acc, 0, 0, 0);
  }
  sq += __shfl_xor(sq, 1); sq += __shfl_xor(sq, 2); sq += __shfl_xor(sq, 4);
  sk += __shfl_xor(sk, 1); sk += __shfl_xor(sk, 2); sk += __shfl_xor(sk, 4);
  if ((tid & 7) == 0) {
    float* np = Np + ((size_t)bh * GSPLIT + split) * 64;
    np[row] = sq;
    np[32 + row] = sk;
  }
  float* gp = Gp + ((size_t)bh * GSPLIT + split) * 1024;
#pragma unroll
  for (int r = 0; r < 4; ++r) {
    int i = wr * 16 + g * 4 + r, j = wc * 16 + lm;
    gp[i * 32 + j] = acc[r];
  }
}

// ---------------------------------------------------------------------------
// Reduce partial Gram/norms, apply 1/(|q||k|)*temp, softmax -> attn[bh][32][32]
// ---------------------------------------------------------------------------
__global__ __launch_bounds__(256) void attn_softmax_kernel(
    const float* __restrict__ Gp, const float* __restrict__ Np,
    const float* __restrict__ temp, float* __restrict__ attn) {
  __shared__ float G[1024];
  __shared__ float qn[32], kn[32];
  int bh = blockIdx.x;
  int tid = threadIdx.x;
  const float* gp = Gp + (size_t)bh * GSPLIT * 1024;
#pragma unroll
  for (int e = tid; e < 1024; e += 256) {
    float s = 0.f;
#pragma unroll
    for (int sp = 0; sp < GSPLIT; ++sp) s += gp[sp * 1024 + e];
    G[e] = s;
  }
  if (tid < 64) {
    const float* np = Np + (size_t)bh * GSPLIT * 64;
    float s = 0.f;
#pragma unroll
    for (int sp = 0; sp < GSPLIT; ++sp) s += np[sp * 64 + tid];
    float nv = fmaxf(sqrtf(s), 1e-12f);
    if (tid < 32) qn[tid] = nv; else kn[tid - 32] = nv;
  }
  __syncthreads();
  if (tid < 32) {
    int c = tid;
    float t = temp[bh & 7];
    float iq = 1.f / qn[c];
    float vals[32];
    float m = -1e30f;
#pragma unroll
    for (int d = 0; d < 32; ++d) {
      float v = G[c * 32 + d] * iq / kn[d] * t;
      vals[d] = v; m = fmaxf(m, v);
    }
    float ss = 0.f;
#pragma unroll
    for (int d = 0; d < 32; ++d) { float e = expf(vals[d] - m); vals[d] = e; ss += e; }
    float inv = 1.f / ss;
#pragma unroll
    for (int d = 0; d < 32; ++d)
      attn[(size_t)bh * 1024 + c * 32 + d] = vals[d] * inv;
  }
}

// ---------------------------------------------------------------------------
// avout_h[b][n][c] (f16, [n][c] layout!) = sum_d attn[b,h,c,d] * v[b,h,d,n]
// ---------------------------------------------------------------------------
__global__ __launch_bounds__(256) void av_kernel(
    const float* __restrict__ qkv, const float* __restrict__ attn,
    _Float16* __restrict__ outh) {
  __shared__ float a_s[1024];
  __shared__ float tr[256 * 33];   // +1 pad word per row -> conflict-free
  int bi = blockIdx.x;           // (b*8+h)*16 + chunk
  int chunk = bi & 15;
  int h = (bi >> 4) & 7;
  int b = bi >> 7;
  int tid = threadIdx.x;
  for (int j = tid; j < 1024; j += 256)
    a_s[j] = attn[((size_t)(b * 8 + h)) * 1024 + j];
  __syncthreads();
  int n = chunk * 256 + tid;
  const float* vbase = qkv + ((size_t)(b * QKV_CH + 512 + h * CH)) * NSP + n;
  float acc[32];
#pragma unroll
  for (int c = 0; c < 32; ++c) acc[c] = 0.f;
#pragma unroll 4
  for (int d = 0; d < 32; ++d) {
    float vv = vbase[(size_t)d * NSP];
#pragma unroll
    for (int c = 0; c < 32; ++c) acc[c] += a_s[c * 32 + d] * vv;
  }
#pragma unroll
  for (int c = 0; c < 32; ++c) tr[tid * 33 + c] = acc[c];
  __syncthreads();
#pragma unroll
  for (int it = 0; it < 4; ++it) {
    int gi = it * 256 + tid;
    int row = gi >> 2, gc = gi & 3;
    half8 hv;
#pragma unroll
    for (int e = 0; e < 8; ++e) hv[e] = (_Float16)tr[row * 33 + gc * 8 + e];
    *(half8*)(outh + ((size_t)(b * NSP + chunk * 256 + row)) * CDIM + h * CH + gc * 8) = hv;
  }
}

// ---------------------------------------------------------------------------
// Weight f32 -> f16 with zero padding. dst [Rd][Cd], src [R][Cs]
// ---------------------------------------------------------------------------
__global__ __launch_bounds__(256) void convw_kernel(
    const float* __restrict__ src, _Float16* __restrict__ dst,
    int R, int Cs, int Cd, int total) {
  int idx = blockIdx.x * 256 + threadIdx.x;
  if (idx >= total) return;
  int r = idx / Cd, c = idx - r * Cd;
  float v = (r < R && c < Cs) ? src[r * Cs + c] : 0.f;
  dst[idx] = (_Float16)v;
}

// ---------------------------------------------------------------------------
// ffn_dw [1360,9] f32 -> wt f16 [2][9][680]: wt[h][ki][c] = kw[(h*680+c)*9+ki]
// ---------------------------------------------------------------------------
__global__ __launch_bounds__(256) void transw_kernel(
    const float* __restrict__ kw, _Float16* __restrict__ wt) {
  int idx = blockIdx.x * 256 + threadIdx.x;
  if (idx >= 2 * 9 * 680) return;
  int h = idx / 6120;
  int rem = idx - h * 6120;
  int ki = rem / 680;
  int c  = rem - ki * 680;
  wt[idx] = (_Float16)kw[(h * 680 + c) * 9 + ki];
}

// ---------------------------------------------------------------------------
// x2 = x + P; P is overwritten IN-PLACE with x2 (f32 [c][n]).
// LN over c -> x2nh [b][n][c] f16 via per-wave LDS transpose
// ---------------------------------------------------------------------------
__global__ __launch_bounds__(256) void ln2_kernel(
    const float* __restrict__ X, float* __restrict__ P,
    const float* __restrict__ w2, const float* __restrict__ b2,
    _Float16* __restrict__ x2nh) {
  __shared__ __align__(16) _Float16 lw[4][64 * 72];  // 72 = 64 + pad
  int tid = threadIdx.x;
  int lane = tid & 63, w = tid >> 6;
  int loc = blockIdx.x * 256 + w * 64 + lane;   // [0, 32768) = b*4096+p
  int b = loc >> 12, p = loc & 4095;
  const float* xp = X + ((size_t)b * CDIM) * NSP + p;
  float* pp = P + ((size_t)b * CDIM) * NSP + p;
  float s = 0.f, s2 = 0.f;
  for (int c = 0; c < CDIM; ++c) {
    float v = xp[(size_t)c * NSP] + pp[(size_t)c * NSP];
    s += v; s2 += v * v;
  }
  float mu = s * (1.f / CDIM);
  float var = s2 * (1.f / CDIM) - mu * mu;
  float inv = 1.0f / sqrtf(var + 1e-5f);
  _Float16* lwp = lw[w];
  int locb = blockIdx.x * 256 + w * 64;
  for (int cc0 = 0; cc0 < CDIM; cc0 += 64) {
    for (int c = cc0; c < cc0 + 64; ++c) {
      float v = xp[(size_t)c * NSP] + pp[(size_t)c * NSP];
      pp[(size_t)c * NSP] = v;    // x2 in-place
      lwp[lane * 72 + (c - cc0)] = (_Float16)((v - mu) * inv * w2[c] + b2[c]);
    }
#pragma unroll
    for (int it = 0; it < 8; ++it) {
      int m = it * 64 + lane;
      int row = m >> 3, cg = m & 7;
      half8 hv = *(const half8*)(lwp + row * 72 + cg * 8);
      *(half8*)(x2nh + ((size_t)(locb + row)) * CDIM + cc0 + cg * 8) = hv;
    }
  }
}

// ---------------------------------------------------------------------------
// Unified f16 MFMA GEMM: D[i][j] = sum_k A[i][k]*B[j][k] (+R), OutT out.
// 128x128 tile, BK=32, 4 waves, global_load_lds staging.
// 1-D grid with chunked-XCD swizzle: each XCD owns one contiguous range
// (= one batch when chunk == gx*gy), so B-panels shared by gx consecutive
// blocks stay in that XCD's L2.
// ---------------------------------------------------------------------------
template <bool RES, typename OutT>
__global__ __launch_bounds__(256) void gemm_f16_kernel(
    const _Float16* __restrict__ A, size_t sA,
    const _Float16* __restrict__ B, size_t sB,
    const float* __restrict__ R, size_t sR,
    OutT* __restrict__ Y, size_t sY,
    int K, int ldy, int Nj, int gx, int gy) {
  __shared__ __align__(16) _Float16 As[128 * 32];
  __shared__ __align__(16) _Float16 Bs[128 * 32];
  int cpx = gx * gy;                         // blocks per XCD chunk
  int sb = (blockIdx.x & 7) * cpx + (blockIdx.x >> 3);
  int bx = sb % gx;
  int tmp = sb / gx;
  int by = tmp % gy;
  int bz = tmp / gy;
  int tid = threadIdx.x;
  int lane = tid & 63;
  int w = tid >> 6;
  int wr = w >> 1, wc = w & 1;
  int lm = lane & 15, g = lane >> 4;
  int i0 = by * 128;
  int j0 = bx * 128;
  const _Float16* Ab = A + (size_t)bz * sA;
  const _Float16* Bb = B + (size_t)bz * sB;

  floatx4 acc[4][4];
#pragma unroll
  for (int mi = 0; mi < 4; ++mi)
#pragma unroll
    for (int ni = 0; ni < 4; ++ni) acc[mi][ni] = {0.f, 0.f, 0.f, 0.f};

  for (int k0 = 0; k0 < K; k0 += 32) {
#pragma unroll
    for (int jj = 0; jj < 2; ++jj) {
      int idx = jj * 256 + tid;
      int row = idx >> 2, gc = idx & 3;
      int base = idx & ~63;        // wave-chunk granule base (uniform per wave)
      gload_lds16(Ab + (size_t)(i0 + row) * K + k0 + gc * 8, As + base * 8);
      gload_lds16(Bb + (size_t)(j0 + row) * K + k0 + gc * 8, Bs + base * 8);
    }
    __syncthreads();
    half8 ha[4], hb[4];
#pragma unroll
    for (int mi = 0; mi < 4; ++mi)
      ha[mi] = *(const half8*)(As + (wr * 64 + mi * 16 + lm) * 32 + g * 8);
#pragma unroll
    for (int ni = 0; ni < 4; ++ni)
      hb[ni] = *(const half8*)(Bs + (wc * 64 + ni * 16 + lm) * 32 + g * 8);
#pragma unroll
    for (int mi = 0; mi < 4; ++mi)
#pragma unroll
      for (int ni = 0; ni < 4; ++ni)
        acc[mi][ni] = __builtin_amdgcn_mfma_f32_16x16x32_f16(
            ha[mi], hb[ni], acc[mi][ni], 0, 0, 0);
    __syncthreads();
  }

  const float* Rb = RES ? (R + (size_t)bz * sR) : nullptr;
  OutT* Yb = Y + (size_t)bz * sY;
#pragma unroll
  for (int mi = 0; mi < 4; ++mi) {
#pragma unroll
    for (int ni = 0; ni < 4; ++ni) {
      int j = j0 + wc * 64 + ni * 16 + lm;
      if (j >= Nj) continue;
#pragma unroll
      for (int r = 0; r < 4; ++r) {
        int i = i0 + wr * 64 + mi * 16 + g * 4 + r;
        size_t o = (size_t)i * ldy + j;
        float v = acc[mi][ni][r];
        if (RES) v += Rb[o];
        Yb[o] = (OutT)v;
      }
    }
  }
}

// ---------------------------------------------------------------------------
// Depthwise 3x3 + exact-gelu gate, [n][c] layout, f16, packed-f16 accum.
// Chunked-XCD swizzle: each XCD gets a contiguous bp strip so the 3-row
// dy-reuse window (~520 KB) stays in its private L2.
// ---------------------------------------------------------------------------
#define DWG_NBLK (BATCH * NSP * 88 / 256)     // 11264, divisible by 8
__global__ __launch_bounds__(256) void dwgate_kernel(
    const _Float16* __restrict__ t, const _Float16* __restrict__ wt,
    _Float16* __restrict__ g) {
  int sb = (blockIdx.x & 7) * (DWG_NBLK / 8) + (blockIdx.x >> 3);
  int idx = sb * 256 + threadIdx.x;           // [0, 32768*88)
  int grp = idx % 88;
  int bp  = idx / 88;                          // b*4096 + p
  int c0 = grp * 8;
  _Float16* gp = g + (size_t)bp * HIDP + c0;
  if (grp >= 85) {                             // K-pad columns 680..703
    half8 z = {};
    *(half8*)gp = z;
    return;
  }
  int p = bp & 4095;
  int y0 = p >> 6, x0 = p & 63;
  const _Float16* tb = t + (size_t)bp * FFN_CH;
  half8 accA = {}, accB = {};
#pragma unroll
  for (int dy = -1; dy <= 1; ++dy) {
    int yy = y0 + dy;
    if ((unsigned)yy > 63u) continue;
#pragma unroll
    for (int dx = -1; dx <= 1; ++dx) {
      int xx = x0 + dx;
      if ((unsigned)xx > 63u) continue;
      int ki = (dy + 1) * 3 + (dx + 1);
      const _Float16* tp = tb + (ptrdiff_t)(dy * 64 + dx) * FFN_CH;
      half8 va = *(const half8*)(tp + c0);
      half8 vb = *(const half8*)(tp + HID + c0);
      half8 wa = *(const half8*)(wt + ki * 680 + c0);
      half8 wb = *(const half8*)(wt + 6120 + ki * 680 + c0);
      accA += va * wa;        // v_pk_fma_f16
      accB += vb * wb;
    }
  }
  half8 r;
#pragma unroll
  for (int e = 0; e < 8; ++e) {
    float a = (float)accA[e];
    float ge = 0.5f * a * (1.f + erff(a * 0.70710678118654752440f));
    r[e] = (_Float16)(ge * (float)accB[e]);
  }
  *(half8*)gp = r;
}

// ---------------------------------------------------------------------------
extern "C" void kernel_launch(void* const* d_in, const int* in_sizes, int n_in,
                              void* d_out, int out_size, void* d_ws, size_t ws_size,
                              hipStream_t stream) {
  const float* x         = (const float*)d_in[0];
  const float* y         = (const float*)d_in[1];
  const float* ln1x_w    = (const float*)d_in[2];
  const float* ln1x_b    = (const float*)d_in[3];
  const float* ln1y_w    = (const float*)d_in[4];
  const float* ln1y_b    = (const float*)d_in[5];
  const float* ln2_w     = (const float*)d_in[6];
  const float* ln2_b     = (const float*)d_in[7];
  const float* temperature = (const float*)d_in[8];
  const float* qkv_dw    = (const float*)d_in[9];
  const float* attn_proj_w = (const float*)d_in[10];
  const float* ffn_in_w  = (const float*)d_in[11];
  const float* ffn_dw    = (const float*)d_in[12];
  const float* ffn_out_w = (const float*)d_in[13];
  float* out = (float*)d_out;
  char* wsb = (char*)d_ws;

  // ---- workspace layout (bytes); same footprint as R4 (~206 MiB) ----
  const size_t SZ_CN4 = (size_t)BATCH * CDIM * NSP * 4;          // 33,554,432
  const size_t off_A   = 0;
  const size_t off_B   = SZ_CN4;
  const size_t off_C   = 2 * SZ_CN4;
  const size_t off_D   = off_C + (size_t)BATCH * QKV_CH * NSP * 4;
  const size_t off_gp  = off_D + 20u * 1024 * 1024;              // 4 MB (dead before g_h)
  const size_t off_np  = off_gp + (size_t)64 * GSPLIT * 1024 * 4;
  const size_t off_sm  = off_D + (size_t)BATCH * NSP * HIDP * 2; // g_h extent
  const size_t off_attn = off_sm;
  const size_t off_wp   = off_attn + 262144;
  const size_t off_wf   = off_wp + (size_t)CDIM * CDIM * 2;
  const size_t off_wo   = off_wf + (size_t)FFNP * CDIM * 2;
  const size_t off_wt   = off_wo + (size_t)CDIM * HIDP * 2;

  float*    xn    = (float*)(wsb + off_A);
  float*    yn    = (float*)(wsb + off_B);
  float*    qkv   = (float*)(wsb + off_C);
  _Float16* tbuf  = (_Float16*)(wsb + off_C);   // after qkv dead
  _Float16* av_h  = (_Float16*)(wsb + off_D);
  _Float16* g_h   = (_Float16*)(wsb + off_D);   // after av_h/Gp/Np dead
  float*    Gp    = (float*)(wsb + off_gp);
  float*    Np    = (float*)(wsb + off_np);
  float*    P     = (float*)(wsb + off_A);      // after xn dead; becomes x2
  _Float16* x2n_h = (_Float16*)(wsb + off_B);   // after yn dead
  float*    attn  = (float*)(wsb + off_attn);
  _Float16* wp_h  = (_Float16*)(wsb + off_wp);
  _Float16* wf_h  = (_Float16*)(wsb + off_wf);
  _Float16* wo_h  = (_Float16*)(wsb + off_wo);
  _Float16* wt_h  = (_Float16*)(wsb + off_wt);

  // ---- weight conversions ----
  convw_kernel<<<(CDIM * CDIM + 255) / 256, 256, 0, stream>>>(
      attn_proj_w, wp_h, CDIM, CDIM, CDIM, CDIM * CDIM);
  convw_kernel<<<(FFNP * CDIM + 255) / 256, 256, 0, stream>>>(
      ffn_in_w, wf_h, FFN_CH, CDIM, CDIM, FFNP * CDIM);
  convw_kernel<<<(CDIM * HIDP + 255) / 256, 256, 0, stream>>>(
      ffn_out_w, wo_h, CDIM, HID, HIDP, CDIM * HIDP);
  transw_kernel<<<48, 256, 0, stream>>>(ffn_dw, wt_h);

  // ---- attention branch ----
  ln_kernel<<<BATCH * NSP / 256, 256, 0, stream>>>(x, ln1x_w, ln1x_b, xn);
  ln_kernel<<<BATCH * NSP / 256, 256, 0, stream>>>(y, ln1y_w, ln1y_b, yn);
  dwconv_qkv_kernel<<<BATCH * 512, 256, 0, stream>>>(xn, yn, qkv_dw, qkv);
  attn_gram_kernel<<<BATCH * HEADS * GSPLIT, 256, 0, stream>>>(qkv, Gp, Np);
  attn_softmax_kernel<<<BATCH * HEADS, 256, 0, stream>>>(Gp, Np, temperature, attn);
  av_kernel<<<BATCH * HEADS * (NSP / 256), 256, 0, stream>>>(qkv, attn, av_h);

  // GEMM1 (flipped): P[b][o][n] = sum_k Wproj[o][k] * av_h[b][n][k]
  gemm_f16_kernel<false, float><<<32 * 2 * BATCH, 256, 0, stream>>>(
      wp_h, (size_t)0, av_h, (size_t)NSP * CDIM, nullptr, (size_t)0,
      P, (size_t)CDIM * NSP, CDIM, NSP, NSP, 32, 2);

  // LN2 fused residual: x2 = x + P (in-place into P); x2n_h (f16 [n][c])
  ln2_kernel<<<BATCH * NSP / 256, 256, 0, stream>>>(x, P, ln2_w, ln2_b, x2n_h);

  // GEMM2: t[b][n][o] = sum_k x2n_h[b][n][k] * wf_h[o][k]  (f16 out)
  gemm_f16_kernel<false, _Float16><<<11 * 32 * BATCH, 256, 0, stream>>>(
      x2n_h, (size_t)NSP * CDIM, wf_h, (size_t)0, nullptr, (size_t)0,
      tbuf, (size_t)NSP * FFN_CH, CDIM, FFN_CH, FFN_CH, 11, 32);

  // depthwise 3x3 + gelu gate -> g_h [b][n][704] f16
  dwgate_kernel<<<DWG_NBLK, 256, 0, stream>>>(tbuf, wt_h, g_h);

  // GEMM3 (flipped, +residual): out = x2 + ffn_out(g)
  gemm_f16_kernel<true, float><<<32 * 2 * BATCH, 256, 0, stream>>>(
      wo_h, (size_t)0, g_h, (size_t)NSP * HIDP, P, (size_t)CDIM * NSP,
      out, (size_t)CDIM * NSP, HIDP, NSP, NSP, 32, 2);
}

// Round 8
// 419.097 us; speedup vs baseline: 2.4930x; 1.1157x over previous
//
#include <hip/hip_runtime.h>
#include <hip/hip_bf16.h>
#include <math.h>

// Problem constants
#define BATCH 8
#define CDIM 256
#define HEADS 8
#define CH 32              // CDIM/HEADS
#define NSP 4096           // 64*64
#define HID 680
#define QKV_CH 768         // 3*CDIM
#define FFN_CH 1360        // 2*HID
#define HIDP 704           // HID padded to mult of 32 (K-pad for GEMM3)
#define FFNP 1408          // FFN_CH padded to mult of 128 (N-pad for GEMM2 weights)
#define GSPLIT 16          // K-splits for the QK^T Gram

typedef _Float16 half8 __attribute__((ext_vector_type(8)));
typedef float floatx4 __attribute__((ext_vector_type(4)));

// async global->LDS, 16B per lane; lds dest = wave-uniform base + lane*16
__device__ inline void gload_lds16(const _Float16* g, _Float16* l) {
  __builtin_amdgcn_global_load_lds(
      (const __attribute__((address_space(1))) unsigned int*)g,
      (__attribute__((address_space(3))) unsigned int*)l, 16, 0, 0);
}

// ---------------------------------------------------------------------------
// Per-position LN stats for BOTH x and y in one launch (full-chip grid).
// muv/invv: [2][B][4096] (0: x, 1: y)
// ---------------------------------------------------------------------------
__global__ __launch_bounds__(256) void lnstat_kernel(
    const float* __restrict__ X, const float* __restrict__ Yv,
    float* __restrict__ muv, float* __restrict__ invv) {
  int idx = blockIdx.x * 256 + threadIdx.x;   // [0, 65536)
  int which = idx >> 15;
  int bp = idx & 32767;
  int b = bp >> 12, p = bp & 4095;
  const float* src = (which ? Yv : X) + ((size_t)b * CDIM) * NSP + p;
  float s = 0.f, s2 = 0.f;
  for (int c = 0; c < CDIM; ++c) {
    float v = src[(size_t)c * NSP];
    s += v; s2 += v * v;
  }
  float mu  = s * (1.f / CDIM);
  float var = s2 * (1.f / CDIM) - mu * mu;
  muv[idx]  = mu;
  invv[idx] = 1.0f / sqrtf(var + 1e-5f);
}

// ---------------------------------------------------------------------------
// Depthwise 3x3 (SAME) with LN fused on-the-fly -> qkv [B,768,4096] f16.
// Block per (b, src-channel-of-512): c<256 -> q from x; c>=256 -> k AND v
// from one y staging (image read once). LN applied during LDS staging.
// ---------------------------------------------------------------------------
__global__ __launch_bounds__(256) void dwconv_qkv_kernel(
    const float* __restrict__ X, const float* __restrict__ Yv,
    const float* __restrict__ w1x, const float* __restrict__ b1x,
    const float* __restrict__ w1y, const float* __restrict__ b1y,
    const float* __restrict__ muv, const float* __restrict__ invv,
    const float* __restrict__ kw, _Float16* __restrict__ out) {
  __shared__ float sm[66 * 68];       // 66 rows x 68 cols, zero border
  int bc = blockIdx.x;                // b*512 + c
  int b = bc >> 9;
  int c = bc & 511;
  bool isq = (c < 256);
  int ch = isq ? c : c - 256;
  const float* src = (isq ? X : Yv) + ((size_t)(b * CDIM + ch)) * NSP;
  const float* mup = muv  + (isq ? 0 : 32768) + b * 4096;
  const float* ivp = invv + (isq ? 0 : 32768) + b * 4096;
  float wc  = (isq ? w1x : w1y)[ch];
  float bcv = (isq ? b1x : b1y)[ch];
  int tid = threadIdx.x;
  for (int i = tid; i < 66 * 68; i += 256) sm[i] = 0.f;
  __syncthreads();
  {
    int r = tid >> 2, xq = (tid & 3) * 16;
    const float* sp = src + r * 64 + xq;
    const float* mp = mup + r * 64 + xq;
    const float* ip = ivp + r * 64 + xq;
    float* lp = sm + (r + 1) * 68 + 1 + xq;
#pragma unroll
    for (int j = 0; j < 4; ++j) {
      float4 v  = ((const float4*)sp)[j];
      float4 m  = ((const float4*)mp)[j];
      float4 iv = ((const float4*)ip)[j];
      lp[j*4+0] = (v.x - m.x) * iv.x * wc + bcv;
      lp[j*4+1] = (v.y - m.y) * iv.y * wc + bcv;
      lp[j*4+2] = (v.z - m.z) * iv.z * wc + bcv;
      lp[j*4+3] = (v.w - m.w) * iv.w * wc + bcv;
    }
  }
  __syncthreads();
  int r = tid >> 2, xs = (tid & 3) * 16;
  float row0[18], row1[18], row2[18];
  {
    const float* q0 = sm + (r + 0) * 68 + xs;
    const float* q1 = sm + (r + 1) * 68 + xs;
    const float* q2 = sm + (r + 2) * 68 + xs;
#pragma unroll
    for (int j = 0; j < 4; ++j) {
      float4 a0 = *(const float4*)(q0 + j * 4);
      float4 a1 = *(const float4*)(q1 + j * 4);
      float4 a2 = *(const float4*)(q2 + j * 4);
      row0[j*4+0]=a0.x; row0[j*4+1]=a0.y; row0[j*4+2]=a0.z; row0[j*4+3]=a0.w;
      row1[j*4+0]=a1.x; row1[j*4+1]=a1.y; row1[j*4+2]=a1.z; row1[j*4+3]=a1.w;
      row2[j*4+0]=a2.x; row2[j*4+1]=a2.y; row2[j*4+2]=a2.z; row2[j*4+3]=a2.w;
    }
    row0[16]=q0[16]; row0[17]=q0[17];
    row1[16]=q1[16]; row1[17]=q1[17];
    row2[16]=q2[16]; row2[17]=q2[17];
  }
  int nouts = isq ? 1 : 2;
  int kcs[2];
  kcs[0] = isq ? c : (256 + ch);
  kcs[1] = 512 + ch;
  for (int oi = 0; oi < nouts; ++oi) {
    int kc = kcs[oi];
    float k9[9];
#pragma unroll
    for (int i = 0; i < 9; ++i) k9[i] = kw[kc * 9 + i];
    float acc[16];
#pragma unroll
    for (int i = 0; i < 16; ++i) {
      acc[i] = row0[i]*k9[0] + row0[i+1]*k9[1] + row0[i+2]*k9[2]
             + row1[i]*k9[3] + row1[i+1]*k9[4] + row1[i+2]*k9[5]
             + row2[i]*k9[6] + row2[i+1]*k9[7] + row2[i+2]*k9[8];
    }
    _Float16* op = out + ((size_t)b * QKV_CH + kc) * NSP + r * 64 + xs;
    half8 h0, h1;
#pragma unroll
    for (int e = 0; e < 8; ++e) { h0[e] = (_Float16)acc[e]; h1[e] = (_Float16)acc[8+e]; }
    ((half8*)op)[0] = h0;
    ((half8*)op)[1] = h1;
  }
}

// ---------------------------------------------------------------------------
// Partial QK^T Gram via MFMA + partial q/k sq-norms (f16 qkv input).
// ---------------------------------------------------------------------------
__global__ __launch_bounds__(256) void attn_gram_kernel(
    const _Float16* __restrict__ qkv, float* __restrict__ Gp,
    float* __restrict__ Np) {
  __shared__ __align__(16) _Float16 lq[32 * 264];
  __shared__ __align__(16) _Float16 lk[32 * 264];
  int bi = blockIdx.x;        // bh*GSPLIT + split
  int split = bi & (GSPLIT - 1);
  int bh = bi / GSPLIT;
  int b = bh >> 3, h = bh & 7;
  int tid = threadIdx.x;
  int row = tid >> 3, cg = (tid & 7) * 32;
  int n0 = split * (NSP / GSPLIT);            // 256 cols
  const _Float16* qp = qkv + ((size_t)(b * QKV_CH) + h * CH + row) * NSP + n0 + cg;
  const _Float16* kp = qkv + ((size_t)(b * QKV_CH) + 256 + h * CH + row) * NSP + n0 + cg;
  float sq = 0.f, sk = 0.f;
  _Float16* lqd = lq + row * 264 + cg;
  _Float16* lkd = lk + row * 264 + cg;
#pragma unroll
  for (int j = 0; j < 4; ++j) {
    half8 hv = *(const half8*)(qp + j * 8);
    half8 hw = *(const half8*)(kp + j * 8);
#pragma unroll
    for (int e = 0; e < 8; ++e) {
      float fq = (float)hv[e]; sq += fq * fq;
      float fk = (float)hw[e]; sk += fk * fk;
    }
    *(half8*)(lqd + j * 8) = hv;
    *(half8*)(lkd + j * 8) = hw;
  }
  __syncthreads();
  int lane = tid & 63, w = tid >> 6;
  int wr = w >> 1, wc = w & 1;
  int lm = lane & 15, g = lane >> 4;
  floatx4 acc = {0.f, 0.f, 0.f, 0.f};
#pragma unroll
  for (int kk = 0; kk < 8; ++kk) {
    half8 av = *(const half8*)(lq + (wr * 16 + lm) * 264 + kk * 32 + g * 8);
    half8 bv = *(const half8*)(lk + (wc * 16 + lm) * 264 + kk * 32 + g * 8);
    acc = __builtin_amdgcn_mfma_f32_16x16x32_f16(av, bv, acc, 0, 0, 0);
  }
  sq += __shfl_xor(sq, 1); sq += __shfl_xor(sq, 2); sq += __shfl_xor(sq, 4);
  sk += __shfl_xor(sk, 1); sk += __shfl_xor(sk, 2); sk += __shfl_xor(sk, 4);
  if ((tid & 7) == 0) {
    float* np = Np + ((size_t)bh * GSPLIT + split) * 64;
    np[row] = sq;
    np[32 + row] = sk;
  }
  float* gp = Gp + ((size_t)bh * GSPLIT + split) * 1024;
#pragma unroll
  for (int r = 0; r < 4; ++r) {
    int i = wr * 16 + g * 4 + r, j = wc * 16 + lm;
    gp[i * 32 + j] = acc[r];
  }
}

// ---------------------------------------------------------------------------
// Reduce partial Gram/norms, apply 1/(|q||k|)*temp, softmax -> attn[bh][32][32]
// ---------------------------------------------------------------------------
__global__ __launch_bounds__(256) void attn_softmax_kernel(
    const float* __restrict__ Gp, const float* __restrict__ Np,
    const float* __restrict__ temp, float* __restrict__ attn) {
  __shared__ float G[1024];
  __shared__ float qn[32], kn[32];
  int bh = blockIdx.x;
  int tid = threadIdx.x;
  const float* gp = Gp + (size_t)bh * GSPLIT * 1024;
#pragma unroll
  for (int e = tid; e < 1024; e += 256) {
    float s = 0.f;
#pragma unroll
    for (int sp = 0; sp < GSPLIT; ++sp) s += gp[sp * 1024 + e];
    G[e] = s;
  }
  if (tid < 64) {
    const float* np = Np + (size_t)bh * GSPLIT * 64;
    float s = 0.f;
#pragma unroll
    for (int sp = 0; sp < GSPLIT; ++sp) s += np[sp * 64 + tid];
    float nv = fmaxf(sqrtf(s), 1e-12f);
    if (tid < 32) qn[tid] = nv; else kn[tid - 32] = nv;
  }
  __syncthreads();
  if (tid < 32) {
    int c = tid;
    float t = temp[bh & 7];
    float iq = 1.f / qn[c];
    float vals[32];
    float m = -1e30f;
#pragma unroll
    for (int d = 0; d < 32; ++d) {
      float v = G[c * 32 + d] * iq / kn[d] * t;
      vals[d] = v; m = fmaxf(m, v);
    }
    float ss = 0.f;
#pragma unroll
    for (int d = 0; d < 32; ++d) { float e = expf(vals[d] - m); vals[d] = e; ss += e; }
    float inv = 1.f / ss;
#pragma unroll
    for (int d = 0; d < 32; ++d)
      attn[(size_t)bh * 1024 + c * 32 + d] = vals[d] * inv;
  }
}

// ---------------------------------------------------------------------------
// avout_h[b][n][c] (f16, [n][c] layout) = sum_d attn[b,h,c,d] * v[b,h,d,n]
// v read from f16 qkv; f32 accumulate.
// ---------------------------------------------------------------------------
__global__ __launch_bounds__(256) void av_kernel(
    const _Float16* __restrict__ qkv, const float* __restrict__ attn,
    _Float16* __restrict__ outh) {
  __shared__ float a_s[1024];
  __shared__ float tr[256 * 33];   // +1 pad word per row -> conflict-free
  int bi = blockIdx.x;           // (b*8+h)*16 + chunk
  int chunk = bi & 15;
  int h = (bi >> 4) & 7;
  int b = bi >> 7;
  int tid = threadIdx.x;
  for (int j = tid; j < 1024; j += 256)
    a_s[j] = attn[((size_t)(b * 8 + h)) * 1024 + j];
  __syncthreads();
  int n = chunk * 256 + tid;
  const _Float16* vbase = qkv + ((size_t)(b * QKV_CH + 512 + h * CH)) * NSP + n;
  float acc[32];
#pragma unroll
  for (int c = 0; c < 32; ++c) acc[c] = 0.f;
#pragma unroll 4
  for (int d = 0; d < 32; ++d) {
    float vv = (float)vbase[(size_t)d * NSP];
#pragma unroll
    for (int c = 0; c < 32; ++c) acc[c] += a_s[c * 32 + d] * vv;
  }
#pragma unroll
  for (int c = 0; c < 32; ++c) tr[tid * 33 + c] = acc[c];
  __syncthreads();
#pragma unroll
  for (int it = 0; it < 4; ++it) {
    int gi = it * 256 + tid;
    int row = gi >> 2, gc = gi & 3;
    half8 hv;
#pragma unroll
    for (int e = 0; e < 8; ++e) hv[e] = (_Float16)tr[row * 33 + gc * 8 + e];
    *(half8*)(outh + ((size_t)(b * NSP + chunk * 256 + row)) * CDIM + h * CH + gc * 8) = hv;
  }
}

// ---------------------------------------------------------------------------
// Weight f32 -> f16 with zero padding. dst [Rd][Cd], src [R][Cs]
// ---------------------------------------------------------------------------
__global__ __launch_bounds__(256) void convw_kernel(
    const float* __restrict__ src, _Float16* __restrict__ dst,
    int R, int Cs, int Cd, int total) {
  int idx = blockIdx.x * 256 + threadIdx.x;
  if (idx >= total) return;
  int r = idx / Cd, c = idx - r * Cd;
  float v = (r < R && c < Cs) ? src[r * Cs + c] : 0.f;
  dst[idx] = (_Float16)v;
}

// ---------------------------------------------------------------------------
// ffn_dw [1360,9] f32 -> wt f16 [2][9][680]: wt[h][ki][c] = kw[(h*680+c)*9+ki]
// ---------------------------------------------------------------------------
__global__ __launch_bounds__(256) void transw_kernel(
    const float* __restrict__ kw, _Float16* __restrict__ wt) {
  int idx = blockIdx.x * 256 + threadIdx.x;
  if (idx >= 2 * 9 * 680) return;
  int h = idx / 6120;
  int rem = idx - h * 6120;
  int ki = rem / 680;
  int c  = rem - ki * 680;
  wt[idx] = (_Float16)kw[(h * 680 + c) * 9 + ki];
}

// ---------------------------------------------------------------------------
// x2 = x + P; P is overwritten IN-PLACE with x2 (f32 [c][n]).
// LN over c -> x2nh [b][n][c] f16 via per-wave LDS transpose
// ---------------------------------------------------------------------------
__global__ __launch_bounds__(256) void ln2_kernel(
    const float* __restrict__ X, float* __restrict__ P,
    const float* __restrict__ w2, const float* __restrict__ b2,
    _Float16* __restrict__ x2nh) {
  __shared__ __align__(16) _Float16 lw[4][64 * 72];  // 72 = 64 + pad
  int tid = threadIdx.x;
  int lane = tid & 63, w = tid >> 6;
  int loc = blockIdx.x * 256 + w * 64 + lane;   // [0, 32768) = b*4096+p
  int b = loc >> 12, p = loc & 4095;
  const float* xp = X + ((size_t)b * CDIM) * NSP + p;
  float* pp = P + ((size_t)b * CDIM) * NSP + p;
  float s = 0.f, s2 = 0.f;
  for (int c = 0; c < CDIM; ++c) {
    float v = xp[(size_t)c * NSP] + pp[(size_t)c * NSP];
    s += v; s2 += v * v;
  }
  float mu = s * (1.f / CDIM);
  float var = s2 * (1.f / CDIM) - mu * mu;
  float inv = 1.0f / sqrtf(var + 1e-5f);
  _Float16* lwp = lw[w];
  int locb = blockIdx.x * 256 + w * 64;
  for (int cc0 = 0; cc0 < CDIM; cc0 += 64) {
    for (int c = cc0; c < cc0 + 64; ++c) {
      float v = xp[(size_t)c * NSP] + pp[(size_t)c * NSP];
      pp[(size_t)c * NSP] = v;    // x2 in-place
      lwp[lane * 72 + (c - cc0)] = (_Float16)((v - mu) * inv * w2[c] + b2[c]);
    }
#pragma unroll
    for (int it = 0; it < 8; ++it) {
      int m = it * 64 + lane;
      int row = m >> 3, cg = m & 7;
      half8 hv = *(const half8*)(lwp + row * 72 + cg * 8);
      *(half8*)(x2nh + ((size_t)(locb + row)) * CDIM + cc0 + cg * 8) = hv;
    }
  }
}

// ---------------------------------------------------------------------------
// Unified f16 MFMA GEMM: D[i][j] = sum_k A[i][k]*B[j][k] (+R), OutT out.
// 128x128 tile, BK=32, 4 waves, global_load_lds staging, chunked-XCD swizzle.
// ---------------------------------------------------------------------------
template <bool RES, typename OutT>
__global__ __launch_bounds__(256) void gemm_f16_kernel(
    const _Float16* __restrict__ A, size_t sA,
    const _Float16* __restrict__ B, size_t sB,
    const float* __restrict__ R, size_t sR,
    OutT* __restrict__ Y, size_t sY,
    int K, int ldy, int Nj, int gx, int gy) {
  __shared__ __align__(16) _Float16 As[128 * 32];
  __shared__ __align__(16) _Float16 Bs[128 * 32];
  int cpx = gx * gy;                         // blocks per XCD chunk
  int sb = (blockIdx.x & 7) * cpx + (blockIdx.x >> 3);
  int bx = sb % gx;
  int tmp = sb / gx;
  int by = tmp % gy;
  int bz = tmp / gy;
  int tid = threadIdx.x;
  int lane = tid & 63;
  int w = tid >> 6;
  int wr = w >> 1, wc = w & 1;
  int lm = lane & 15, g = lane >> 4;
  int i0 = by * 128;
  int j0 = bx * 128;
  const _Float16* Ab = A + (size_t)bz * sA;
  const _Float16* Bb = B + (size_t)bz * sB;

  floatx4 acc[4][4];
#pragma unroll
  for (int mi = 0; mi < 4; ++mi)
#pragma unroll
    for (int ni = 0; ni < 4; ++ni) acc[mi][ni] = {0.f, 0.f, 0.f, 0.f};

  for (int k0 = 0; k0 < K; k0 += 32) {
#pragma unroll
    for (int jj = 0; jj < 2; ++jj) {
      int idx = jj * 256 + tid;
      int row = idx >> 2, gc = idx & 3;
      int base = idx & ~63;        // wave-chunk granule base (uniform per wave)
      gload_lds16(Ab + (size_t)(i0 + row) * K + k0 + gc * 8, As + base * 8);
      gload_lds16(Bb + (size_t)(j0 + row) * K + k0 + gc * 8, Bs + base * 8);
    }
    __syncthreads();
    half8 ha[4], hb[4];
#pragma unroll
    for (int mi = 0; mi < 4; ++mi)
      ha[mi] = *(const half8*)(As + (wr * 64 + mi * 16 + lm) * 32 + g * 8);
#pragma unroll
    for (int ni = 0; ni < 4; ++ni)
      hb[ni] = *(const half8*)(Bs + (wc * 64 + ni * 16 + lm) * 32 + g * 8);
#pragma unroll
    for (int mi = 0; mi < 4; ++mi)
#pragma unroll
      for (int ni = 0; ni < 4; ++ni)
        acc[mi][ni] = __builtin_amdgcn_mfma_f32_16x16x32_f16(
            ha[mi], hb[ni], acc[mi][ni], 0, 0, 0);
    __syncthreads();
  }

  const float* Rb = RES ? (R + (size_t)bz * sR) : nullptr;
  OutT* Yb = Y + (size_t)bz * sY;
#pragma unroll
  for (int mi = 0; mi < 4; ++mi) {
#pragma unroll
    for (int ni = 0; ni < 4; ++ni) {
      int j = j0 + wc * 64 + ni * 16 + lm;
      if (j >= Nj) continue;
#pragma unroll
      for (int r = 0; r < 4; ++r) {
        int i = i0 + wr * 64 + mi * 16 + g * 4 + r;
        size_t o = (size_t)i * ldy + j;
        float v = acc[mi][ni][r];
        if (RES) v += Rb[o];
        Yb[o] = (OutT)v;
      }
    }
  }
}

// ---------------------------------------------------------------------------
// Depthwise 3x3 + exact-gelu gate, [n][c] layout, f16, packed-f16 accum.
// Thread = 16-row y-strip x 8 channels; 3x3x2 neighborhood kept in a rolling
// register window (load only row y+1 each step: 6 loads per output row
// instead of 18 -> ~4.7x fewer VMEM instructions).
// ---------------------------------------------------------------------------
#define DWG_NBLK (BATCH * 64 * 4 * 88 / 256)   // 704
__global__ __launch_bounds__(256) void dwgate_kernel(
    const _Float16* __restrict__ t, const _Float16* __restrict__ wt,
    _Float16* __restrict__ g) {
  int idx = blockIdx.x * 256 + threadIdx.x;    // [0, 180224)
  int cg = idx % 88;
  int rest = idx / 88;                          // b*256 + x*4 + ys
  int ys = rest & 3;
  int x0 = (rest >> 2) & 63;
  int b  = rest >> 8;
  int c0 = cg * 8;
  int ybeg = ys * 16;
  size_t gbase = ((size_t)(b * 4096 + ybeg * 64 + x0)) * HIDP + c0;
  if (cg >= 85) {                               // K-pad columns 680..703
    half8 z = {};
#pragma unroll
    for (int yi = 0; yi < 16; ++yi)
      *(half8*)(g + gbase + (size_t)yi * 64 * HIDP) = z;
    return;
  }
  half8 wa[9], wb[9];
#pragma unroll
  for (int k = 0; k < 9; ++k) {
    wa[k] = *(const half8*)(wt + k * 680 + c0);
    wb[k] = *(const half8*)(wt + 6120 + k * 680 + c0);
  }
  const _Float16* tb = t + ((size_t)b * 4096) * FFN_CH + c0;
  auto LDA = [&](int yy, int xx) -> half8 {
    half8 z = {};
    if ((unsigned)yy > 63u || (unsigned)xx > 63u) return z;
    return *(const half8*)(tb + ((size_t)(yy * 64 + xx)) * FFN_CH);
  };
  auto LDB = [&](int yy, int xx) -> half8 {
    half8 z = {};
    if ((unsigned)yy > 63u || (unsigned)xx > 63u) return z;
    return *(const half8*)(tb + ((size_t)(yy * 64 + xx)) * FFN_CH + HID);
  };
  half8 rA[3][3], rB[3][3];
#pragma unroll
  for (int dx = 0; dx < 3; ++dx) {
    rA[0][dx] = LDA(ybeg - 1, x0 + dx - 1); rB[0][dx] = LDB(ybeg - 1, x0 + dx - 1);
    rA[1][dx] = LDA(ybeg,     x0 + dx - 1); rB[1][dx] = LDB(ybeg,     x0 + dx - 1);
  }
#pragma unroll
  for (int yi = 0; yi < 16; ++yi) {
    int yn = ybeg + yi + 1;
#pragma unroll
    for (int dx = 0; dx < 3; ++dx) {
      rA[2][dx] = LDA(yn, x0 + dx - 1);
      rB[2][dx] = LDB(yn, x0 + dx - 1);
    }
    half8 accA = {}, accB = {};
#pragma unroll
    for (int r = 0; r < 3; ++r)
#pragma unroll
      for (int dx = 0; dx < 3; ++dx) {
        accA += rA[r][dx] * wa[r * 3 + dx];    // v_pk_fma_f16
        accB += rB[r][dx] * wb[r * 3 + dx];
      }
    half8 res;
#pragma unroll
    for (int e = 0; e < 8; ++e) {
      float a = (float)accA[e];
      float ge = 0.5f * a * (1.f + erff(a * 0.70710678118654752440f));
      res[e] = (_Float16)(ge * (float)accB[e]);
    }
    *(half8*)(g + gbase + (size_t)yi * 64 * HIDP) = res;
#pragma unroll
    for (int dx = 0; dx < 3; ++dx) {
      rA[0][dx] = rA[1][dx]; rA[1][dx] = rA[2][dx];
      rB[0][dx] = rB[1][dx]; rB[1][dx] = rB[2][dx];
    }
  }
}

// ---------------------------------------------------------------------------
extern "C" void kernel_launch(void* const* d_in, const int* in_sizes, int n_in,
                              void* d_out, int out_size, void* d_ws, size_t ws_size,
                              hipStream_t stream) {
  const float* x         = (const float*)d_in[0];
  const float* y         = (const float*)d_in[1];
  const float* ln1x_w    = (const float*)d_in[2];
  const float* ln1x_b    = (const float*)d_in[3];
  const float* ln1y_w    = (const float*)d_in[4];
  const float* ln1y_b    = (const float*)d_in[5];
  const float* ln2_w     = (const float*)d_in[6];
  const float* ln2_b     = (const float*)d_in[7];
  const float* temperature = (const float*)d_in[8];
  const float* qkv_dw    = (const float*)d_in[9];
  const float* attn_proj_w = (const float*)d_in[10];
  const float* ffn_in_w  = (const float*)d_in[11];
  const float* ffn_dw    = (const float*)d_in[12];
  const float* ffn_out_w = (const float*)d_in[13];
  float* out = (float*)d_out;
  char* wsb = (char*)d_ws;

  // ---- workspace layout (bytes); ~206 MiB ----
  // Region A [0, 32M):    P (f32) -> x2 (in-place)
  // Region B [32M, 64M):  x2n_h (f16)
  // Region C [64M, 160M): qkv (f16, 48M) -> tbuf (f16, 85M)
  // Region D [160M, 204M): av_h (f16) + Gp/Np @ +20M -> g_h (f16, 44M)
  // smalls   [204M, ...):  attn, wp_h, wf_h, wo_h, wt_h, muv, invv
  const size_t SZ_CN4 = (size_t)BATCH * CDIM * NSP * 4;          // 33,554,432
  const size_t off_A   = 0;
  const size_t off_B   = SZ_CN4;
  const size_t off_C   = 2 * SZ_CN4;
  const size_t off_D   = off_C + (size_t)BATCH * QKV_CH * NSP * 4;
  const size_t off_gp  = off_D + 20u * 1024 * 1024;              // 4 MB (dead before g_h)
  const size_t off_np  = off_gp + (size_t)64 * GSPLIT * 1024 * 4;
  const size_t off_sm  = off_D + (size_t)BATCH * NSP * HIDP * 2; // g_h extent
  const size_t off_attn = off_sm;
  const size_t off_wp   = off_attn + 262144;
  const size_t off_wf   = off_wp + (size_t)CDIM * CDIM * 2;
  const size_t off_wo   = off_wf + (size_t)FFNP * CDIM * 2;
  const size_t off_wt   = off_wo + (size_t)CDIM * HIDP * 2;
  const size_t off_mu   = off_wt + 32768;
  const size_t off_iv   = off_mu + 262144;

  _Float16* qkv   = (_Float16*)(wsb + off_C);
  _Float16* tbuf  = (_Float16*)(wsb + off_C);   // after qkv dead
  _Float16* av_h  = (_Float16*)(wsb + off_D);
  _Float16* g_h   = (_Float16*)(wsb + off_D);   // after av_h/Gp/Np dead
  float*    Gp    = (float*)(wsb + off_gp);
  float*    Np    = (float*)(wsb + off_np);
  float*    P     = (float*)(wsb + off_A);      // GEMM1 out; becomes x2
  _Float16* x2n_h = (_Float16*)(wsb + off_B);
  float*    attn  = (float*)(wsb + off_attn);
  _Float16* wp_h  = (_Float16*)(wsb + off_wp);
  _Float16* wf_h  = (_Float16*)(wsb + off_wf);
  _Float16* wo_h  = (_Float16*)(wsb + off_wo);
  _Float16* wt_h  = (_Float16*)(wsb + off_wt);
  float*    muv   = (float*)(wsb + off_mu);
  float*    invv  = (float*)(wsb + off_iv);

  // ---- weight conversions ----
  convw_kernel<<<(CDIM * CDIM + 255) / 256, 256, 0, stream>>>(
      attn_proj_w, wp_h, CDIM, CDIM, CDIM, CDIM * CDIM);
  convw_kernel<<<(FFNP * CDIM + 255) / 256, 256, 0, stream>>>(
      ffn_in_w, wf_h, FFN_CH, CDIM, CDIM, FFNP * CDIM);
  convw_kernel<<<(CDIM * HIDP + 255) / 256, 256, 0, stream>>>(
      ffn_out_w, wo_h, CDIM, HID, HIDP, CDIM * HIDP);
  transw_kernel<<<48, 256, 0, stream>>>(ffn_dw, wt_h);

  // ---- attention branch ----
  lnstat_kernel<<<256, 256, 0, stream>>>(x, y, muv, invv);
  dwconv_qkv_kernel<<<BATCH * 512, 256, 0, stream>>>(
      x, y, ln1x_w, ln1x_b, ln1y_w, ln1y_b, muv, invv, qkv_dw, qkv);
  attn_gram_kernel<<<BATCH * HEADS * GSPLIT, 256, 0, stream>>>(qkv, Gp, Np);
  attn_softmax_kernel<<<BATCH * HEADS, 256, 0, stream>>>(Gp, Np, temperature, attn);
  av_kernel<<<BATCH * HEADS * (NSP / 256), 256, 0, stream>>>(qkv, attn, av_h);

  // GEMM1 (flipped): P[b][o][n] = sum_k Wproj[o][k] * av_h[b][n][k]
  gemm_f16_kernel<false, float><<<32 * 2 * BATCH, 256, 0, stream>>>(
      wp_h, (size_t)0, av_h, (size_t)NSP * CDIM, nullptr, (size_t)0,
      P, (size_t)CDIM * NSP, CDIM, NSP, NSP, 32, 2);

  // LN2 fused residual: x2 = x + P (in-place into P); x2n_h (f16 [n][c])
  ln2_kernel<<<BATCH * NSP / 256, 256, 0, stream>>>(x, P, ln2_w, ln2_b, x2n_h);

  // GEMM2: t[b][n][o] = sum_k x2n_h[b][n][k] * wf_h[o][k]  (f16 out)
  gemm_f16_kernel<false, _Float16><<<11 * 32 * BATCH, 256, 0, stream>>>(
      x2n_h, (size_t)NSP * CDIM, wf_h, (size_t)0, nullptr, (size_t)0,
      tbuf, (size_t)NSP * FFN_CH, CDIM, FFN_CH, FFN_CH, 11, 32);

  // depthwise 3x3 + gelu gate -> g_h [b][n][704] f16
  dwgate_kernel<<<DWG_NBLK, 256, 0, stream>>>(tbuf, wt_h, g_h);

  // GEMM3 (flipped, +residual): out = x2 + ffn_out(g)
  gemm_f16_kernel<true, float><<<32 * 2 * BATCH, 256, 0, stream>>>(
      wo_h, (size_t)0, g_h, (size_t)NSP * HIDP, P, (size_t)CDIM * NSP,
      out, (size_t)CDIM * NSP, HIDP, NSP, NSP, 32, 2);
}

// Round 10
// 382.322 us; speedup vs baseline: 2.7328x; 1.0962x over previous
//
#include <hip/hip_runtime.h>
#include <hip/hip_bf16.h>
#include <math.h>

// Problem constants
#define BATCH 8
#define CDIM 256
#define HEADS 8
#define CH 32              // CDIM/HEADS
#define NSP 4096           // 64*64
#define HID 680
#define QKV_CH 768         // 3*CDIM
#define FFN_CH 1360        // 2*HID
#define HIDP 704           // HID padded to mult of 32 (K-pad for GEMM3)
#define FFNP 1408          // FFN_CH padded to mult of 128 (N-pad for GEMM2 weights)
#define GSPLIT 16          // K-splits for the QK^T Gram

typedef _Float16 half8 __attribute__((ext_vector_type(8)));
typedef float floatx4 __attribute__((ext_vector_type(4)));

// async global->LDS, 16B per lane; lds dest = wave-uniform base + lane*16
__device__ inline void gload_lds16(const _Float16* g, _Float16* l) {
  __builtin_amdgcn_global_load_lds(
      (const __attribute__((address_space(1))) unsigned int*)g,
      (__attribute__((address_space(3))) unsigned int*)l, 16, 0, 0);
}

// ---------------------------------------------------------------------------
// Per-position LN stats for BOTH x and y in one launch (full-chip grid).
// muv/invv: [2][B][4096] (0: x, 1: y)
// ---------------------------------------------------------------------------
__global__ __launch_bounds__(256) void lnstat_kernel(
    const float* __restrict__ X, const float* __restrict__ Yv,
    float* __restrict__ muv, float* __restrict__ invv) {
  int idx = blockIdx.x * 256 + threadIdx.x;   // [0, 65536)
  int which = idx >> 15;
  int bp = idx & 32767;
  int b = bp >> 12, p = bp & 4095;
  const float* src = (which ? Yv : X) + ((size_t)b * CDIM) * NSP + p;
  float s = 0.f, s2 = 0.f;
  for (int c = 0; c < CDIM; ++c) {
    float v = src[(size_t)c * NSP];
    s += v; s2 += v * v;
  }
  float mu  = s * (1.f / CDIM);
  float var = s2 * (1.f / CDIM) - mu * mu;
  muv[idx]  = mu;
  invv[idx] = 1.0f / sqrtf(var + 1e-5f);
}

// ---------------------------------------------------------------------------
// Depthwise 3x3 (SAME) with LN fused on-the-fly -> qkv [B,768,4096] f16.
// Block per (b, src-channel-of-512): c<256 -> q from x; c>=256 -> k AND v
// from one y staging (image read once). LN applied during LDS staging.
// ---------------------------------------------------------------------------
__global__ __launch_bounds__(256) void dwconv_qkv_kernel(
    const float* __restrict__ X, const float* __restrict__ Yv,
    const float* __restrict__ w1x, const float* __restrict__ b1x,
    const float* __restrict__ w1y, const float* __restrict__ b1y,
    const float* __restrict__ muv, const float* __restrict__ invv,
    const float* __restrict__ kw, _Float16* __restrict__ out) {
  __shared__ float sm[66 * 68];       // 66 rows x 68 cols, zero border
  int bc = blockIdx.x;                // b*512 + c
  int b = bc >> 9;
  int c = bc & 511;
  bool isq = (c < 256);
  int ch = isq ? c : c - 256;
  const float* src = (isq ? X : Yv) + ((size_t)(b * CDIM + ch)) * NSP;
  const float* mup = muv  + (isq ? 0 : 32768) + b * 4096;
  const float* ivp = invv + (isq ? 0 : 32768) + b * 4096;
  float wc  = (isq ? w1x : w1y)[ch];
  float bcv = (isq ? b1x : b1y)[ch];
  int tid = threadIdx.x;
  for (int i = tid; i < 66 * 68; i += 256) sm[i] = 0.f;
  __syncthreads();
  {
    int r = tid >> 2, xq = (tid & 3) * 16;
    const float* sp = src + r * 64 + xq;
    const float* mp = mup + r * 64 + xq;
    const float* ip = ivp + r * 64 + xq;
    float* lp = sm + (r + 1) * 68 + 1 + xq;
#pragma unroll
    for (int j = 0; j < 4; ++j) {
      float4 v  = ((const float4*)sp)[j];
      float4 m  = ((const float4*)mp)[j];
      float4 iv = ((const float4*)ip)[j];
      lp[j*4+0] = (v.x - m.x) * iv.x * wc + bcv;
      lp[j*4+1] = (v.y - m.y) * iv.y * wc + bcv;
      lp[j*4+2] = (v.z - m.z) * iv.z * wc + bcv;
      lp[j*4+3] = (v.w - m.w) * iv.w * wc + bcv;
    }
  }
  __syncthreads();
  int r = tid >> 2, xs = (tid & 3) * 16;
  float row0[18], row1[18], row2[18];
  {
    const float* q0 = sm + (r + 0) * 68 + xs;
    const float* q1 = sm + (r + 1) * 68 + xs;
    const float* q2 = sm + (r + 2) * 68 + xs;
#pragma unroll
    for (int j = 0; j < 4; ++j) {
      float4 a0 = *(const float4*)(q0 + j * 4);
      float4 a1 = *(const float4*)(q1 + j * 4);
      float4 a2 = *(const float4*)(q2 + j * 4);
      row0[j*4+0]=a0.x; row0[j*4+1]=a0.y; row0[j*4+2]=a0.z; row0[j*4+3]=a0.w;
      row1[j*4+0]=a1.x; row1[j*4+1]=a1.y; row1[j*4+2]=a1.z; row1[j*4+3]=a1.w;
      row2[j*4+0]=a2.x; row2[j*4+1]=a2.y; row2[j*4+2]=a2.z; row2[j*4+3]=a2.w;
    }
    row0[16]=q0[16]; row0[17]=q0[17];
    row1[16]=q1[16]; row1[17]=q1[17];
    row2[16]=q2[16]; row2[17]=q2[17];
  }
  int nouts = isq ? 1 : 2;
  int kcs[2];
  kcs[0] = isq ? c : (256 + ch);
  kcs[1] = 512 + ch;
  for (int oi = 0; oi < nouts; ++oi) {
    int kc = kcs[oi];
    float k9[9];
#pragma unroll
    for (int i = 0; i < 9; ++i) k9[i] = kw[kc * 9 + i];
    float acc[16];
#pragma unroll
    for (int i = 0; i < 16; ++i) {
      acc[i] = row0[i]*k9[0] + row0[i+1]*k9[1] + row0[i+2]*k9[2]
             + row1[i]*k9[3] + row1[i+1]*k9[4] + row1[i+2]*k9[5]
             + row2[i]*k9[6] + row2[i+1]*k9[7] + row2[i+2]*k9[8];
    }
    _Float16* op = out + ((size_t)b * QKV_CH + kc) * NSP + r * 64 + xs;
    half8 h0, h1;
#pragma unroll
    for (int e = 0; e < 8; ++e) { h0[e] = (_Float16)acc[e]; h1[e] = (_Float16)acc[8+e]; }
    ((half8*)op)[0] = h0;
    ((half8*)op)[1] = h1;
  }
}

// ---------------------------------------------------------------------------
// Partial QK^T Gram via MFMA + partial q/k sq-norms (f16 qkv input).
// ---------------------------------------------------------------------------
__global__ __launch_bounds__(256) void attn_gram_kernel(
    const _Float16* __restrict__ qkv, float* __restrict__ Gp,
    float* __restrict__ Np) {
  __shared__ __align__(16) _Float16 lq[32 * 264];
  __shared__ __align__(16) _Float16 lk[32 * 264];
  int bi = blockIdx.x;        // bh*GSPLIT + split
  int split = bi & (GSPLIT - 1);
  int bh = bi / GSPLIT;
  int b = bh >> 3, h = bh & 7;
  int tid = threadIdx.x;
  int row = tid >> 3, cg = (tid & 7) * 32;
  int n0 = split * (NSP / GSPLIT);            // 256 cols
  const _Float16* qp = qkv + ((size_t)(b * QKV_CH) + h * CH + row) * NSP + n0 + cg;
  const _Float16* kp = qkv + ((size_t)(b * QKV_CH) + 256 + h * CH + row) * NSP + n0 + cg;
  float sq = 0.f, sk = 0.f;
  _Float16* lqd = lq + row * 264 + cg;
  _Float16* lkd = lk + row * 264 + cg;
#pragma unroll
  for (int j = 0; j < 4; ++j) {
    half8 hv = *(const half8*)(qp + j * 8);
    half8 hw = *(const half8*)(kp + j * 8);
#pragma unroll
    for (int e = 0; e < 8; ++e) {
      float fq = (float)hv[e]; sq += fq * fq;
      float fk = (float)hw[e]; sk += fk * fk;
    }
    *(half8*)(lqd + j * 8) = hv;
    *(half8*)(lkd + j * 8) = hw;
  }
  __syncthreads();
  int lane = tid & 63, w = tid >> 6;
  int wr = w >> 1, wc = w & 1;
  int lm = lane & 15, g = lane >> 4;
  floatx4 acc = {0.f, 0.f, 0.f, 0.f};
#pragma unroll
  for (int kk = 0; kk < 8; ++kk) {
    half8 av = *(const half8*)(lq + (wr * 16 + lm) * 264 + kk * 32 + g * 8);
    half8 bv = *(const half8*)(lk + (wc * 16 + lm) * 264 + kk * 32 + g * 8);
    acc = __builtin_amdgcn_mfma_f32_16x16x32_f16(av, bv, acc, 0, 0, 0);
  }
  sq += __shfl_xor(sq, 1); sq += __shfl_xor(sq, 2); sq += __shfl_xor(sq, 4);
  sk += __shfl_xor(sk, 1); sk += __shfl_xor(sk, 2); sk += __shfl_xor(sk, 4);
  if ((tid & 7) == 0) {
    float* np = Np + ((size_t)bh * GSPLIT + split) * 64;
    np[row] = sq;
    np[32 + row] = sk;
  }
  float* gp = Gp + ((size_t)bh * GSPLIT + split) * 1024;
#pragma unroll
  for (int r = 0; r < 4; ++r) {
    int i = wr * 16 + g * 4 + r, j = wc * 16 + lm;
    gp[i * 32 + j] = acc[r];
  }
}

// ---------------------------------------------------------------------------
// Reduce partial Gram/norms, apply 1/(|q||k|)*temp, softmax -> attn[bh][32][32]
// ---------------------------------------------------------------------------
__global__ __launch_bounds__(256) void attn_softmax_kernel(
    const float* __restrict__ Gp, const float* __restrict__ Np,
    const float* __restrict__ temp, float* __restrict__ attn) {
  __shared__ float G[1024];
  __shared__ float qn[32], kn[32];
  int bh = blockIdx.x;
  int tid = threadIdx.x;
  const float* gp = Gp + (size_t)bh * GSPLIT * 1024;
#pragma unroll
  for (int e = tid; e < 1024; e += 256) {
    float s = 0.f;
#pragma unroll
    for (int sp = 0; sp < GSPLIT; ++sp) s += gp[sp * 1024 + e];
    G[e] = s;
  }
  if (tid < 64) {
    const float* np = Np + (size_t)bh * GSPLIT * 64;
    float s = 0.f;
#pragma unroll
    for (int sp = 0; sp < GSPLIT; ++sp) s += np[sp * 64 + tid];
    float nv = fmaxf(sqrtf(s), 1e-12f);
    if (tid < 32) qn[tid] = nv; else kn[tid - 32] = nv;
  }
  __syncthreads();
  if (tid < 32) {
    int c = tid;
    float t = temp[bh & 7];
    float iq = 1.f / qn[c];
    float vals[32];
    float m = -1e30f;
#pragma unroll
    for (int d = 0; d < 32; ++d) {
      float v = G[c * 32 + d] * iq / kn[d] * t;
      vals[d] = v; m = fmaxf(m, v);
    }
    float ss = 0.f;
#pragma unroll
    for (int d = 0; d < 32; ++d) { float e = expf(vals[d] - m); vals[d] = e; ss += e; }
    float inv = 1.f / ss;
#pragma unroll
    for (int d = 0; d < 32; ++d)
      attn[(size_t)bh * 1024 + c * 32 + d] = vals[d] * inv;
  }
}

// ---------------------------------------------------------------------------
// avout_h[b][n][c] (f16, [n][c] layout) = sum_d attn[b,h,c,d] * v[b,h,d,n]
// ---------------------------------------------------------------------------
__global__ __launch_bounds__(256) void av_kernel(
    const _Float16* __restrict__ qkv, const float* __restrict__ attn,
    _Float16* __restrict__ outh) {
  __shared__ float a_s[1024];
  __shared__ float tr[256 * 33];   // +1 pad word per row -> conflict-free
  int bi = blockIdx.x;           // (b*8+h)*16 + chunk
  int chunk = bi & 15;
  int h = (bi >> 4) & 7;
  int b = bi >> 7;
  int tid = threadIdx.x;
  for (int j = tid; j < 1024; j += 256)
    a_s[j] = attn[((size_t)(b * 8 + h)) * 1024 + j];
  __syncthreads();
  int n = chunk * 256 + tid;
  const _Float16* vbase = qkv + ((size_t)(b * QKV_CH + 512 + h * CH)) * NSP + n;
  float acc[32];
#pragma unroll
  for (int c = 0; c < 32; ++c) acc[c] = 0.f;
#pragma unroll 4
  for (int d = 0; d < 32; ++d) {
    float vv = (float)vbase[(size_t)d * NSP];
#pragma unroll
    for (int c = 0; c < 32; ++c) acc[c] += a_s[c * 32 + d] * vv;
  }
#pragma unroll
  for (int c = 0; c < 32; ++c) tr[tid * 33 + c] = acc[c];
  __syncthreads();
#pragma unroll
  for (int it = 0; it < 4; ++it) {
    int gi = it * 256 + tid;
    int row = gi >> 2, gc = gi & 3;
    half8 hv;
#pragma unroll
    for (int e = 0; e < 8; ++e) hv[e] = (_Float16)tr[row * 33 + gc * 8 + e];
    *(half8*)(outh + ((size_t)(b * NSP + chunk * 256 + row)) * CDIM + h * CH + gc * 8) = hv;
  }
}

// ---------------------------------------------------------------------------
// Weight f32 -> f16 with zero padding. dst [Rd][Cd], src [R][Cs]
// ---------------------------------------------------------------------------
__global__ __launch_bounds__(256) void convw_kernel(
    const float* __restrict__ src, _Float16* __restrict__ dst,
    int R, int Cs, int Cd, int total) {
  int idx = blockIdx.x * 256 + threadIdx.x;
  if (idx >= total) return;
  int r = idx / Cd, c = idx - r * Cd;
  float v = (r < R && c < Cs) ? src[r * Cs + c] : 0.f;
  dst[idx] = (_Float16)v;
}

// ---------------------------------------------------------------------------
// ffn_dw [1360,9] f32 -> wt f16 [2][9][680]: wt[h][ki][c] = kw[(h*680+c)*9+ki]
// ---------------------------------------------------------------------------
__global__ __launch_bounds__(256) void transw_kernel(
    const float* __restrict__ kw, _Float16* __restrict__ wt) {
  int idx = blockIdx.x * 256 + threadIdx.x;
  if (idx >= 2 * 9 * 680) return;
  int h = idx / 6120;
  int rem = idx - h * 6120;
  int ki = rem / 680;
  int c  = rem - ki * 680;
  wt[idx] = (_Float16)kw[(h * 680 + c) * 9 + ki];
}

// ---------------------------------------------------------------------------
// x2 = x + P; P is overwritten IN-PLACE with x2 (f32 [c][n]).
// LN over c -> x2nh [b][n][c] f16 via per-wave LDS transpose
// ---------------------------------------------------------------------------
__global__ __launch_bounds__(256) void ln2_kernel(
    const float* __restrict__ X, float* __restrict__ P,
    const float* __restrict__ w2, const float* __restrict__ b2,
    _Float16* __restrict__ x2nh) {
  __shared__ __align__(16) _Float16 lw[4][64 * 72];  // 72 = 64 + pad
  int tid = threadIdx.x;
  int lane = tid & 63, w = tid >> 6;
  int loc = blockIdx.x * 256 + w * 64 + lane;   // [0, 32768) = b*4096+p
  int b = loc >> 12, p = loc & 4095;
  const float* xp = X + ((size_t)b * CDIM) * NSP + p;
  float* pp = P + ((size_t)b * CDIM) * NSP + p;
  float s = 0.f, s2 = 0.f;
  for (int c = 0; c < CDIM; ++c) {
    float v = xp[(size_t)c * NSP] + pp[(size_t)c * NSP];
    s += v; s2 += v * v;
  }
  float mu = s * (1.f / CDIM);
  float var = s2 * (1.f / CDIM) - mu * mu;
  float inv = 1.0f / sqrtf(var + 1e-5f);
  _Float16* lwp = lw[w];
  int locb = blockIdx.x * 256 + w * 64;
  for (int cc0 = 0; cc0 < CDIM; cc0 += 64) {
    for (int c = cc0; c < cc0 + 64; ++c) {
      float v = xp[(size_t)c * NSP] + pp[(size_t)c * NSP];
      pp[(size_t)c * NSP] = v;    // x2 in-place
      lwp[lane * 72 + (c - cc0)] = (_Float16)((v - mu) * inv * w2[c] + b2[c]);
    }
#pragma unroll
    for (int it = 0; it < 8; ++it) {
      int m = it * 64 + lane;
      int row = m >> 3, cg = m & 7;
      half8 hv = *(const half8*)(lwp + row * 72 + cg * 8);
      *(half8*)(x2nh + ((size_t)(locb + row)) * CDIM + cc0 + cg * 8) = hv;
    }
  }
}

// ---------------------------------------------------------------------------
// Unified f16 MFMA GEMM: D[i][j] = sum_k A[i][k]*B[j][k] (+R), OutT out.
// 128x128 tile, BK=32, 4 waves, global_load_lds staging, chunked-XCD swizzle.
// ---------------------------------------------------------------------------
template <bool RES, typename OutT>
__global__ __launch_bounds__(256) void gemm_f16_kernel(
    const _Float16* __restrict__ A, size_t sA,
    const _Float16* __restrict__ B, size_t sB,
    const float* __restrict__ R, size_t sR,
    OutT* __restrict__ Y, size_t sY,
    int K, int ldy, int Nj, int gx, int gy) {
  __shared__ __align__(16) _Float16 As[128 * 32];
  __shared__ __align__(16) _Float16 Bs[128 * 32];
  int cpx = gx * gy;                         // blocks per XCD chunk
  int sb = (blockIdx.x & 7) * cpx + (blockIdx.x >> 3);
  int bx = sb % gx;
  int tmp = sb / gx;
  int by = tmp % gy;
  int bz = tmp / gy;
  int tid = threadIdx.x;
  int lane = tid & 63;
  int w = tid >> 6;
  int wr = w >> 1, wc = w & 1;
  int lm = lane & 15, g = lane >> 4;
  int i0 = by * 128;
  int j0 = bx * 128;
  const _Float16* Ab = A + (size_t)bz * sA;
  const _Float16* Bb = B + (size_t)bz * sB;

  floatx4 acc[4][4];
#pragma unroll
  for (int mi = 0; mi < 4; ++mi)
#pragma unroll
    for (int ni = 0; ni < 4; ++ni) acc[mi][ni] = {0.f, 0.f, 0.f, 0.f};

  for (int k0 = 0; k0 < K; k0 += 32) {
#pragma unroll
    for (int jj = 0; jj < 2; ++jj) {
      int idx = jj * 256 + tid;
      int row = idx >> 2, gc = idx & 3;
      int base = idx & ~63;        // wave-chunk granule base (uniform per wave)
      gload_lds16(Ab + (size_t)(i0 + row) * K + k0 + gc * 8, As + base * 8);
      gload_lds16(Bb + (size_t)(j0 + row) * K + k0 + gc * 8, Bs + base * 8);
    }
    __syncthreads();
    half8 ha[4], hb[4];
#pragma unroll
    for (int mi = 0; mi < 4; ++mi)
      ha[mi] = *(const half8*)(As + (wr * 64 + mi * 16 + lm) * 32 + g * 8);
#pragma unroll
    for (int ni = 0; ni < 4; ++ni)
      hb[ni] = *(const half8*)(Bs + (wc * 64 + ni * 16 + lm) * 32 + g * 8);
#pragma unroll
    for (int mi = 0; mi < 4; ++mi)
#pragma unroll
      for (int ni = 0; ni < 4; ++ni)
        acc[mi][ni] = __builtin_amdgcn_mfma_f32_16x16x32_f16(
            ha[mi], hb[ni], acc[mi][ni], 0, 0, 0);
    __syncthreads();
  }

  const float* Rb = RES ? (R + (size_t)bz * sR) : nullptr;
  OutT* Yb = Y + (size_t)bz * sY;
#pragma unroll
  for (int mi = 0; mi < 4; ++mi) {
#pragma unroll
    for (int ni = 0; ni < 4; ++ni) {
      int j = j0 + wc * 64 + ni * 16 + lm;
      if (j >= Nj) continue;
#pragma unroll
      for (int r = 0; r < 4; ++r) {
        int i = i0 + wr * 64 + mi * 16 + g * 4 + r;
        size_t o = (size_t)i * ldy + j;
        float v = acc[mi][ni][r];
        if (RES) v += Rb[o];
        Yb[o] = (OutT)v;
      }
    }
  }
}

// ---------------------------------------------------------------------------
// Depthwise 3x3 + exact-gelu gate, [n][c] layout, f16, packed-f16 accum.
// Thread = 4-row y-strip x 8 channels; rolling register window (6 loads/row).
// 2816 blocks (full occupancy) + chunked-XCD swizzle: each XCD owns one
// batch; consecutive rest = consecutive x so the dx-halo is L1/L2-hot and
// ys-halo rows are same-XCD L2 hits.
// ---------------------------------------------------------------------------
#define DWG_S 4
#define DWG_NBLK (BATCH * 64 * (64 / DWG_S) * 88 / 256)   // 2816, %8==0
__global__ __launch_bounds__(256) void dwgate_kernel(
    const _Float16* __restrict__ t, const _Float16* __restrict__ wt,
    _Float16* __restrict__ g) {
  int bid = (blockIdx.x & 7) * (DWG_NBLK / 8) + (blockIdx.x >> 3);
  int idx = bid * 256 + threadIdx.x;           // [0, 720896)
  int cg = idx % 88;
  int rest = idx / 88;                          // b*1024 + ys*64 + x
  int x0 = rest & 63;
  int ys = (rest >> 6) & 15;
  int b  = rest >> 10;
  int c0 = cg * 8;
  int ybeg = ys * DWG_S;
  size_t gbase = ((size_t)(b * 4096 + ybeg * 64 + x0)) * HIDP + c0;
  if (cg >= 85) {                               // K-pad columns 680..703
    half8 z = {};
#pragma unroll
    for (int yi = 0; yi < DWG_S; ++yi)
      *(half8*)(g + gbase + (size_t)yi * 64 * HIDP) = z;
    return;
  }
  half8 wa[9], wb[9];
#pragma unroll
  for (int k = 0; k < 9; ++k) {
    wa[k] = *(const half8*)(wt + k * 680 + c0);
    wb[k] = *(const half8*)(wt + 6120 + k * 680 + c0);
  }
  const _Float16* tb = t + ((size_t)b * 4096) * FFN_CH + c0;
  auto LDA = [&](int yy, int xx) -> half8 {
    half8 z = {};
    if ((unsigned)yy > 63u || (unsigned)xx > 63u) return z;
    return *(const half8*)(tb + ((size_t)(yy * 64 + xx)) * FFN_CH);
  };
  auto LDB = [&](int yy, int xx) -> half8 {
    half8 z = {};
    if ((unsigned)yy > 63u || (unsigned)xx > 63u) return z;
    return *(const half8*)(tb + ((size_t)(yy * 64 + xx)) * FFN_CH + HID);
  };
  half8 rA[3][3], rB[3][3];
#pragma unroll
  for (int dx = 0; dx < 3; ++dx) {
    rA[0][dx] = LDA(ybeg - 1, x0 + dx - 1); rB[0][dx] = LDB(ybeg - 1, x0 + dx - 1);
    rA[1][dx] = LDA(ybeg,     x0 + dx - 1); rB[1][dx] = LDB(ybeg,     x0 + dx - 1);
  }
#pragma unroll
  for (int yi = 0; yi < DWG_S; ++yi) {
    int yn = ybeg + yi + 1;
#pragma unroll
    for (int dx = 0; dx < 3; ++dx) {
      rA[2][dx] = LDA(yn, x0 + dx - 1);
      rB[2][dx] = LDB(yn, x0 + dx - 1);
    }
    half8 accA = {}, accB = {};
#pragma unroll
    for (int r = 0; r < 3; ++r)
#pragma unroll
      for (int dx = 0; dx < 3; ++dx) {
        accA += rA[r][dx] * wa[r * 3 + dx];    // v_pk_fma_f16
        accB += rB[r][dx] * wb[r * 3 + dx];
      }
    half8 res;
#pragma unroll
    for (int e = 0; e < 8; ++e) {
      float a = (float)accA[e];
      float ge = 0.5f * a * (1.f + erff(a * 0.70710678118654752440f));
      res[e] = (_Float16)(ge * (float)accB[e]);
    }
    *(half8*)(g + gbase + (size_t)yi * 64 * HIDP) = res;
#pragma unroll
    for (int dx = 0; dx < 3; ++dx) {
      rA[0][dx] = rA[1][dx]; rA[1][dx] = rA[2][dx];
      rB[0][dx] = rB[1][dx]; rB[1][dx] = rB[2][dx];
    }
  }
}

// ---------------------------------------------------------------------------
extern "C" void kernel_launch(void* const* d_in, const int* in_sizes, int n_in,
                              void* d_out, int out_size, void* d_ws, size_t ws_size,
                              hipStream_t stream) {
  const float* x         = (const float*)d_in[0];
  const float* y         = (const float*)d_in[1];
  const float* ln1x_w    = (const float*)d_in[2];
  const float* ln1x_b    = (const float*)d_in[3];
  const float* ln1y_w    = (const float*)d_in[4];
  const float* ln1y_b    = (const float*)d_in[5];
  const float* ln2_w     = (const float*)d_in[6];
  const float* ln2_b     = (const float*)d_in[7];
  const float* temperature = (const float*)d_in[8];
  const float* qkv_dw    = (const float*)d_in[9];
  const float* attn_proj_w = (const float*)d_in[10];
  const float* ffn_in_w  = (const float*)d_in[11];
  const float* ffn_dw    = (const float*)d_in[12];
  const float* ffn_out_w = (const float*)d_in[13];
  float* out = (float*)d_out;
  char* wsb = (char*)d_ws;

  // ---- workspace layout (bytes); ~206 MiB ----
  const size_t SZ_CN4 = (size_t)BATCH * CDIM * NSP * 4;          // 33,554,432
  const size_t off_A   = 0;
  const size_t off_B   = SZ_CN4;
  const size_t off_C   = 2 * SZ_CN4;
  const size_t off_D   = off_C + (size_t)BATCH * QKV_CH * NSP * 4;
  const size_t off_gp  = off_D + 20u * 1024 * 1024;              // 4 MB (dead before g_h)
  const size_t off_np  = off_gp + (size_t)64 * GSPLIT * 1024 * 4;
  const size_t off_sm  = off_D + (size_t)BATCH * NSP * HIDP * 2; // g_h extent
  const size_t off_attn = off_sm;
  const size_t off_wp   = off_attn + 262144;
  const size_t off_wf   = off_wp + (size_t)CDIM * CDIM * 2;
  const size_t off_wo   = off_wf + (size_t)FFNP * CDIM * 2;
  const size_t off_wt   = off_wo + (size_t)CDIM * HIDP * 2;
  const size_t off_mu   = off_wt + 32768;
  const size_t off_iv   = off_mu + 262144;

  _Float16* qkv   = (_Float16*)(wsb + off_C);
  _Float16* tbuf  = (_Float16*)(wsb + off_C);   // after qkv dead
  _Float16* av_h  = (_Float16*)(wsb + off_D);
  _Float16* g_h   = (_Float16*)(wsb + off_D);   // after av_h/Gp/Np dead
  float*    Gp    = (float*)(wsb + off_gp);
  float*    Np    = (float*)(wsb + off_np);
  float*    P     = (float*)(wsb + off_A);      // GEMM1 out; becomes x2
  _Float16* x2n_h = (_Float16*)(wsb + off_B);
  float*    attn  = (float*)(wsb + off_attn);
  _Float16* wp_h  = (_Float16*)(wsb + off_wp);
  _Float16* wf_h  = (_Float16*)(wsb + off_wf);
  _Float16* wo_h  = (_Float16*)(wsb + off_wo);
  _Float16* wt_h  = (_Float16*)(wsb + off_wt);
  float*    muv   = (float*)(wsb + off_mu);
  float*    invv  = (float*)(wsb + off_iv);

  // ---- weight conversions ----
  convw_kernel<<<(CDIM * CDIM + 255) / 256, 256, 0, stream>>>(
      attn_proj_w, wp_h, CDIM, CDIM, CDIM, CDIM * CDIM);
  convw_kernel<<<(FFNP * CDIM + 255) / 256, 256, 0, stream>>>(
      ffn_in_w, wf_h, FFN_CH, CDIM, CDIM, FFNP * CDIM);
  convw_kernel<<<(CDIM * HIDP + 255) / 256, 256, 0, stream>>>(
      ffn_out_w, wo_h, CDIM, HID, HIDP, CDIM * HIDP);
  transw_kernel<<<48, 256, 0, stream>>>(ffn_dw, wt_h);

  // ---- attention branch ----
  lnstat_kernel<<<256, 256, 0, stream>>>(x, y, muv, invv);
  dwconv_qkv_kernel<<<BATCH * 512, 256, 0, stream>>>(
      x, y, ln1x_w, ln1x_b, ln1y_w, ln1y_b, muv, invv, qkv_dw, qkv);
  attn_gram_kernel<<<BATCH * HEADS * GSPLIT, 256, 0, stream>>>(qkv, Gp, Np);
  attn_softmax_kernel<<<BATCH * HEADS, 256, 0, stream>>>(Gp, Np, temperature, attn);
  av_kernel<<<BATCH * HEADS * (NSP / 256), 256, 0, stream>>>(qkv, attn, av_h);

  // GEMM1 (flipped): P[b][o][n] = sum_k Wproj[o][k] * av_h[b][n][k]
  gemm_f16_kernel<false, float><<<32 * 2 * BATCH, 256, 0, stream>>>(
      wp_h, (size_t)0, av_h, (size_t)NSP * CDIM, nullptr, (size_t)0,
      P, (size_t)CDIM * NSP, CDIM, NSP, NSP, 32, 2);

  // LN2 fused residual: x2 = x + P (in-place into P); x2n_h (f16 [n][c])
  ln2_kernel<<<BATCH * NSP / 256, 256, 0, stream>>>(x, P, ln2_w, ln2_b, x2n_h);

  // GEMM2: t[b][n][o] = sum_k x2n_h[b][n][k] * wf_h[o][k]  (f16 out)
  gemm_f16_kernel<false, _Float16><<<11 * 32 * BATCH, 256, 0, stream>>>(
      x2n_h, (size_t)NSP * CDIM, wf_h, (size_t)0, nullptr, (size_t)0,
      tbuf, (size_t)NSP * FFN_CH, CDIM, FFN_CH, FFN_CH, 11, 32);

  // depthwise 3x3 + gelu gate -> g_h [b][n][704] f16
  dwgate_kernel<<<DWG_NBLK, 256, 0, stream>>>(tbuf, wt_h, g_h);

  // GEMM3 (flipped, +residual): out = x2 + ffn_out(g)
  gemm_f16_kernel<true, float><<<32 * 2 * BATCH, 256, 0, stream>>>(
      wo_h, (size_t)0, g_h, (size_t)NSP * HIDP, P, (size_t)CDIM * NSP,
      out, (size_t)CDIM * NSP, HIDP, NSP, NSP, 32, 2);
}